// Round 4
// baseline (557.736 us; speedup 1.0000x reference)
//
#include <hip/hip_runtime.h>
#include <hip/hip_cooperative_groups.h>
#include <stdint.h>

namespace cg = cooperative_groups;

#define B_ 8
#define N_ 4000
#define C_ 80
#define NC_ (N_ * C_)          // 320000 candidates per image
#define KP_ 2048               // K_PRE
#define CAND_ 4096             // compaction capacity = SLOTS_*SLOTCAP_
#define SLOTS_ 32
#define SLOTCAP_ 128
#define DET_ 100
#define NW_ 32                 // u64 words per NMS row (2048 bits)
#define CLIP_ 4.135166556742356f

#define PB_ 80                 // proposals per scores block
#define IB_ (N_ / PB_)         // 50 blocks per image
#define CB_ 64                 // coarse bins
#define FB_ 128                // fine bins
#define NBLK_ ((NC_ / 4 + 255) / 256)   // 313 per-image blocks for refine/compact

#define RT_ 256                // threads per rank block
#define RI_ 4                  // i-keys per thread
#define RJS_ 16                // j-slices
#define RSL_ (CAND_ / RJS_)    // 256 keys per slice
#define RIB_ (CAND_ / (RT_ * RI_))  // 4 i-blocks per image
#define IBK_ (CAND_ / 256)     // 16 scatter blocks per image

#define GB_ 512                // cooperative grid: 2 blocks/CU co-resident

typedef unsigned long long u64;

__device__ __forceinline__ void decode4(const float4 pr, const float4 d,
                                        float& x1, float& y1, float& x2, float& y2) {
  float w = pr.z - pr.x, h = pr.w - pr.y;
  float cx = pr.x + 0.5f * w, cy = pr.y + 0.5f * h;
  float dx = d.x / 10.0f, dy = d.y / 10.0f;
  float dw = fminf(d.z / 5.0f, CLIP_), dh = fminf(d.w / 5.0f, CLIP_);
  float pcx = dx * w + cx, pcy = dy * h + cy;
  float pw = expf(dw) * w, ph = expf(dh) * h;
  x1 = pcx - 0.5f * pw; y1 = pcy - 0.5f * ph;
  x2 = pcx + 0.5f * pw; y2 = pcy + 0.5f * ph;
}

// ---------------- LDS union for the mega-kernel phases ----------------
struct SmScores { float lds[PB_ * 81]; float mArr[PB_]; float dArr[PB_]; uint32_t hcnt[CB_]; };
struct SmSel { int s_cb; uint32_t s_tail; uint32_t s_thr; };
struct SmSup { float4 shj[4][64]; float sha[4][64]; };
union SmAll { SmScores sc; SmSel sel; u64 rk[RSL_]; SmSup sup; };

// ================= MEGA-KERNEL: all phases, 1 dispatch =================
// Round-3 budget: modeled kernel work ~35-45us vs dur 183.7us — the gap is
// ~8 dependent dispatches x ~10us launch/drain bubble. Fuse everything into
// one cooperative kernel; grid.sync() (device-scope fence) replaces each
// kernel boundary. 512 blocks x 256 thr, __launch_bounds__(256,2): 2
// blocks/CU co-resident (LDS 26.2KB, VGPR<=256).
__global__ __launch_bounds__(256, 2) void k_mega(
    const float* __restrict__ logits, const float* __restrict__ bbox,
    const float* __restrict__ props,
    uint32_t* __restrict__ keys, uint32_t* __restrict__ imgHist,
    uint32_t* __restrict__ fineHist, uint32_t* __restrict__ cnt,
    u64* __restrict__ cand, float* __restrict__ topScore,
    int* __restrict__ topLabel, float* __restrict__ topBox,
    float* __restrict__ nmsBox, u64* __restrict__ sup,
    uint32_t* __restrict__ rankPart, float* __restrict__ out,
    uint4* __restrict__ zeroPtr, int zeroN4) {
  cg::grid_group grid = cg::this_grid();
  __shared__ SmAll sm;
  int bid = blockIdx.x, t = threadIdx.x;

  // ---- phase 0: zero hists/cnt/cand/top arrays (replaces memsetAsync) ----
  for (int i = bid * 256 + t; i < zeroN4; i += GB_ * 256)
    zeroPtr[i] = make_uint4(0u, 0u, 0u, 0u);
  grid.sync();

  // ---- phase 1: fused softmax + keys + coarse histogram (400 vb) ----
  if (bid < B_ * IB_) {
    int b = bid / IB_, lb = bid - b * IB_;
    int p0 = b * N_ + lb * PB_;
    if (t < CB_) sm.sc.hcnt[t] = 0;
    const float4* src = (const float4*)(logits + (size_t)p0 * 81);
    for (int k = t; k < PB_ * 81 / 4; k += 256) ((float4*)sm.sc.lds)[k] = src[k];
    __syncthreads();
    if (t < PB_) {
      const float* lp = sm.sc.lds + t * 81;
      float m = lp[0];
      for (int i = 1; i <= C_; ++i) m = fmaxf(m, lp[i]);
      float denom = 0.f;
      for (int i = 0; i <= C_; ++i) denom += expf(lp[i] - m);
      sm.sc.mArr[t] = m; sm.sc.dArr[t] = denom;
    }
    __syncthreads();
#pragma unroll
    for (int iter = 0; iter < PB_ * C_ / 256; ++iter) {   // 25 iters
      int e = iter * 256 + t;
      int pp = e / C_, c = e - pp * C_;
      float lv = sm.sc.lds[pp * 81 + c + 1];
      float score = expf(lv - sm.sc.mArr[pp]) / sm.sc.dArr[pp];
      uint32_t key = 0;
      if (score > 0.01f) {
        key = __float_as_uint(score);
        atomicAdd(&sm.sc.hcnt[(key >> 20) - 960], 1u);
      }
      keys[(size_t)p0 * C_ + e] = key;
    }
    __syncthreads();
    if (t < CB_ && sm.sc.hcnt[t]) atomicAdd(&imgHist[b * CB_ + t], sm.sc.hcnt[t]);
  }
  grid.sync();

  // ---- phase 2: fine histogram (2504 vb) ----
  for (int vb = bid; vb < B_ * NBLK_; vb += GB_) {
    __syncthreads();                    // guard sm.sel reuse across iterations
    int b = vb / NBLK_, lb = vb - b * NBLK_;
    if (t < 64) {
      uint32_t v = imgHist[b * CB_ + t];
#pragma unroll
      for (int d = 1; d < 64; d <<= 1) {
        uint32_t o = __shfl_down(v, d);
        v += (t + d < 64) ? o : 0;
      }
      uint32_t nxt = __shfl_down(v, 1);
      if (t == 63) nxt = 0;
      uint32_t total = __shfl(v, 0);
      if (t == 0 && total < KP_) sm.sel.s_cb = -1;
      if (total >= KP_ && v >= KP_ && nxt < KP_) sm.sel.s_cb = t;
    }
    __syncthreads();
    int cb = sm.sel.s_cb;
    if (cb >= 0) {
      int ti = lb * 256 + t;
      if (ti < NC_ / 4) {
        uint4 k4 = ((const uint4*)(keys + (size_t)b * NC_))[ti];
        uint32_t want = (uint32_t)(cb + 960);
        uint32_t kv[4] = {k4.x, k4.y, k4.z, k4.w};
#pragma unroll
        for (int q = 0; q < 4; ++q)
          if ((kv[q] >> 20) == want)
            atomicAdd(&fineHist[b * FB_ + ((kv[q] >> 13) & (FB_ - 1))], 1u);
      }
    }
  }
  grid.sync();

  // ---- phase 3: threshold + compact into slots (2504 vb) ----
  for (int vb = bid; vb < B_ * NBLK_; vb += GB_) {
    __syncthreads();                    // guard sm.sel reuse across iterations
    int b = vb / NBLK_, lb = vb - b * NBLK_;
    if (t < 64) {
      uint32_t v = imgHist[b * CB_ + t];
#pragma unroll
      for (int d = 1; d < 64; d <<= 1) {
        uint32_t o = __shfl_down(v, d);
        v += (t + d < 64) ? o : 0;
      }
      uint32_t nxt = __shfl_down(v, 1);
      if (t == 63) nxt = 0;
      uint32_t total = __shfl(v, 0);
      if (t == 0 && total < KP_) { sm.sel.s_cb = -1; sm.sel.s_tail = 0; }
      if (total >= KP_ && v >= KP_ && nxt < KP_) { sm.sel.s_cb = t; sm.sel.s_tail = nxt; }
    }
    __syncthreads();
    int cb = sm.sel.s_cb;
    if (cb < 0) {
      if (t == 0) sm.sel.s_thr = 1u;
    } else if (t < 64) {
      uint32_t f0 = fineHist[b * FB_ + 2 * t];
      uint32_t f1 = fineHist[b * FB_ + 2 * t + 1];
      uint32_t v = f0 + f1;
#pragma unroll
      for (int d = 1; d < 64; d <<= 1) {
        uint32_t o = __shfl_down(v, d);
        v += (t + d < 64) ? o : 0;
      }
      uint32_t nxt = __shfl_down(v, 1);
      if (t == 63) nxt = 0;
      uint32_t tail = sm.sel.s_tail;
      bool c0 = (tail + v >= KP_);
      bool c1 = (tail + nxt + f1 >= KP_);
      bool cN = (tail + nxt >= KP_);
      if (c0 && !c1) sm.sel.s_thr = ((uint32_t)(cb + 960) << 20) | ((uint32_t)(2 * t) << 13);
      if (c1 && !cN) sm.sel.s_thr = ((uint32_t)(cb + 960) << 20) | ((uint32_t)(2 * t + 1) << 13);
    }
    __syncthreads();
    uint32_t thrb = sm.sel.s_thr;
    int ti = lb * 256 + t;
    if (ti < NC_ / 4) {
      uint4 k4 = ((const uint4*)(keys + (size_t)b * NC_))[ti];
      int slot = (ti >> 4) & (SLOTS_ - 1);
      uint32_t kv[4] = {k4.x, k4.y, k4.z, k4.w};
      int ns = 0;
#pragma unroll
      for (int q = 0; q < 4; ++q) ns += (kv[q] >= thrb) ? 1 : 0;
      if (ns != 0) {
        uint32_t pos = atomicAdd(&cnt[(b * SLOTS_ + slot) * 16], (uint32_t)ns);
        u64* seg = cand + (size_t)b * CAND_ + slot * SLOTCAP_;
        uint32_t baseIdx = (uint32_t)(ti * 4);
#pragma unroll
        for (int q = 0; q < 4; ++q) {
          if (kv[q] >= thrb) {
            if (pos < SLOTCAP_)
              seg[pos] = ((u64)kv[q] << 32) | (uint32_t)(~(baseIdx + q));
            ++pos;
          }
        }
      }
    }
  }
  grid.sync();

  // ---- phase 4: i-blocked j-split rank (512 vb exact) ----
  {
    int b = bid / (RIB_ * RJS_);
    int rem = bid - b * (RIB_ * RJS_);
    int lb = rem / RJS_, js = rem - lb * RJS_;
    const u64* cb2 = cand + (size_t)b * CAND_;
    if (t < RSL_ / 2)
      ((ulonglong2*)sm.rk)[t] = ((const ulonglong2*)(cb2 + js * RSL_))[t];
    int base = lb * (RT_ * RI_) + t;
    u64 ki[RI_];
#pragma unroll
    for (int q = 0; q < RI_; ++q) ki[q] = cb2[base + q * RT_];
    __syncthreads();
    int cnt4[RI_] = {0, 0, 0, 0};
#pragma unroll 4
    for (int j2 = 0; j2 < RSL_ / 2; ++j2) {
      ulonglong2 v = ((const ulonglong2*)sm.rk)[j2];
#pragma unroll
      for (int q = 0; q < RI_; ++q) {
        cnt4[q] += (v.x > ki[q]) ? 1 : 0;
        cnt4[q] += (v.y > ki[q]) ? 1 : 0;
      }
    }
    uint32_t* rp = rankPart + ((size_t)(b * RJS_ + js)) * CAND_ + base;
#pragma unroll
    for (int q = 0; q < RI_; ++q) rp[q * RT_] = (uint32_t)cnt4[q];
  }
  grid.sync();

  // ---- phase 5: sum partial ranks + decode + scatter (128 vb) ----
  if (bid < B_ * IBK_) {
    int b = bid / IBK_, lb = bid - b * IBK_;
    int i = lb * 256 + t;
    u64 ki = cand[(size_t)b * CAND_ + i];
    if (ki != 0ull) {
      uint32_t r = 0;
#pragma unroll
      for (int js = 0; js < RJS_; ++js)
        r += rankPart[((size_t)(b * RJS_ + js)) * CAND_ + i];
      if (r < KP_) {
        uint32_t sbits = (uint32_t)(ki >> 32);
        uint32_t idx = ~((uint32_t)ki);
        int n = idx / C_, c = idx % C_;
        float4 pr4 = ((const float4*)props)[(size_t)b * N_ + n];
        float4 d = ((const float4*)(bbox + ((size_t)b * N_ + n) * ((C_ + 1) * 4)))[c + 1];
        float x1, y1, x2, y2;
        decode4(pr4, d, x1, y1, x2, y2);
        float off = (float)(c + 1) * 4096.0f;
        size_t o = (size_t)b * KP_ + (size_t)r;
        topScore[o] = __uint_as_float(sbits);
        topLabel[o] = c + 1;
        ((float4*)topBox)[o] = make_float4(x1, y1, x2, y2);
        ((float4*)nmsBox)[o] = make_float4(x1 + off, y1 + off, x2 + off, y2 + off);
      }
    }
  }
  grid.sync();

  // ---- phase 6: suppression bitmatrix (4224 tiles, 4 waves/block, 3 passes)
  // Barriers hoisted OUTSIDE the tile guard (tt varies per wave) so they stay
  // block-uniform; each wave uses its own LDS region.
  {
    int l = t & 63, wv = t >> 6;
    for (int pass = 0; pass < (B_ * 528 + GB_ * 4 - 1) / (GB_ * 4); ++pass) {
      int tt = pass * GB_ * 4 + bid * 4 + wv;
      bool act = tt < B_ * 528;
      int b = 0, tj = 0, i = 0;
      float4 bi = make_float4(0.f, 0.f, 0.f, 0.f);
      float areai = 0.f;
      __syncthreads();                  // LDS region reuse vs previous pass
      if (act) {
        b = tt / 528;
        int r = tt - b * 528;
        int ti2 = 0, rem2 = r;
        while (rem2 >= 32 - ti2) { rem2 -= 32 - ti2; ++ti2; }
        tj = ti2 + rem2;
        const float4* boxes = (const float4*)(nmsBox + (size_t)b * KP_ * 4);
        float4 bj0 = boxes[tj * 64 + l];
        sm.sup.shj[wv][l] = bj0;
        sm.sup.sha[wv][l] = fmaxf(bj0.z - bj0.x, 0.f) * fmaxf(bj0.w - bj0.y, 0.f);
        i = ti2 * 64 + l;
        bi = boxes[i];
        areai = fmaxf(bi.z - bi.x, 0.f) * fmaxf(bi.w - bi.y, 0.f);
      }
      __syncthreads();                  // writes visible (block-uniform barrier)
      if (act) {
        u64 bits = 0;
        for (int jj = 0; jj < 64; ++jj) {
          int j = tj * 64 + jj;
          if (j > i) {
            float4 bj = sm.sup.shj[wv][jj];
            float ltx = fmaxf(bi.x, bj.x), lty = fmaxf(bi.y, bj.y);
            float rbx = fminf(bi.z, bj.z), rby = fminf(bi.w, bj.w);
            float iw = fmaxf(rbx - ltx, 0.f), ih = fmaxf(rby - lty, 0.f);
            float inter = iw * ih;
            float uni = areai + sm.sup.sha[wv][jj] - inter;
            float iou = inter / fmaxf(uni, 1e-9f);
            if (iou > 0.5f) bits |= (1ull << jj);
          }
        }
        sup[((size_t)b * KP_ + i) * NW_ + tj] = bits;
      }
    }
  }
  grid.sync();

  // ---- phase 7: greedy NMS scan + output (8 images, wave 0 of blocks 0..7)
  if (bid < B_ && t < 64) {
    int b = bid, l = t;
    int h = l >> 5, w = l & 31;
    const u64* base = sup + (size_t)b * KP_ * NW_;
    const float* ts = topScore + (size_t)b * KP_;
    const int* tl = topLabel + (size_t)b * KP_;
    const float4* tb = (const float4*)(topBox + (size_t)b * KP_ * 4);
    unsigned m32 = 0;
#pragma unroll
    for (int j = 0; j < 8; ++j) {
      float4 s4 = ((const float4*)ts)[l * 8 + j];
      if (!(s4.x > 0.f)) m32 |= 1u << (4 * j + 0);
      if (!(s4.y > 0.f)) m32 |= 1u << (4 * j + 1);
      if (!(s4.z > 0.f)) m32 |= 1u << (4 * j + 2);
      if (!(s4.w > 0.f)) m32 |= 1u << (4 * j + 3);
    }
    u64 removed = ((u64)__shfl(m32, 2 * w + 1) << 32) | (u64)__shfl(m32, 2 * w);

    int outCount = 0;                                  // wave-uniform
    auto emitRow = [&](int row, bool kept) {
      if (l == (outCount & 63)) {
        float4 bx = tb[row];
        out[((size_t)b * DET_ + outCount) * 4 + 0] = bx.x;
        out[((size_t)b * DET_ + outCount) * 4 + 1] = bx.y;
        out[((size_t)b * DET_ + outCount) * 4 + 2] = bx.z;
        out[((size_t)b * DET_ + outCount) * 4 + 3] = bx.w;
        out[B_ * DET_ * 4 + (size_t)b * DET_ + outCount] = kept ? ts[row] : -1.0f;
        out[B_ * DET_ * 4 + B_ * DET_ + (size_t)b * DET_ + outCount] = (float)tl[row];
      }
      ++outCount;
    };

    u64 ra[32], rb[32];
    auto loadc = [&](u64* dst, int c) {
      const u64* p = base + ((size_t)c * 64 + h * 32) * NW_ + w;
#pragma unroll
      for (int k = 0; k < 32; ++k) dst[k] = p[(size_t)k * NW_];
    };
    auto chunk = [&](u64* cur, int c) -> bool {        // returns done
      u64 rm = __shfl(removed, c);
      unsigned rml = (unsigned)rm, rmh = (unsigned)(rm >> 32);
#pragma unroll
      for (int k = 0; k < 32; ++k) {
        unsigned dlo = __builtin_amdgcn_readlane((unsigned)cur[k], c);
        unsigned dhi = __builtin_amdgcn_readlane((unsigned)(cur[k] >> 32), c);
        if (!((rml >> k) & 1u)) { rml |= dlo; rmh |= dhi; }
      }
#pragma unroll
      for (int k = 0; k < 32; ++k) {
        unsigned dlo = __builtin_amdgcn_readlane((unsigned)cur[k], 32 + c);
        unsigned dhi = __builtin_amdgcn_readlane((unsigned)(cur[k] >> 32), 32 + c);
        if (!((rmh >> k) & 1u)) { rml |= dlo; rmh |= dhi; }
      }
      u64 rmfull = ((u64)rmh << 32) | rml;
      u64 kb = ~rmfull;
      while (kb) {
        if (outCount >= DET_) return true;
        int k = __builtin_ctzll(kb);
        kb &= kb - 1;
        emitRow(c * 64 + k, true);
      }
      if (outCount >= DET_) return true;
      unsigned kmask = h ? ~rmh : ~rml;
      u64 acc = 0;
#pragma unroll
      for (int k = 0; k < 32; ++k)
        acc |= ((kmask >> k) & 1u) ? cur[k] : 0ull;
      acc |= __shfl_xor(acc, 32);
      removed = (l == c) ? rmfull : removed;
      if (l < 32 && l >= c) removed |= acc;
      return false;
    };

    bool done = false;
    loadc(ra, 0);
    for (int c = 0; c < NW_ && !done; c += 2) {
      if (c + 1 < NW_) loadc(rb, c + 1);
      done = chunk(ra, c);
      if (!done) {
        if (c + 2 < NW_) loadc(ra, c + 2);
        done = chunk(rb, c + 1);
      }
    }
    if (outCount < DET_) {
      for (int c2 = 0; c2 < NW_ && outCount < DET_; ++c2) {
        u64 rm = __shfl(removed, c2);
        while (rm && outCount < DET_) {
          int k = __builtin_ctzll(rm);
          rm &= rm - 1;
          emitRow(c2 * 64 + k, false);
        }
      }
    }
  }
}

// ================= fallback: the proven 8-dispatch path =================
__global__ __launch_bounds__(256) void k_scores(const float* __restrict__ logits,
                                                uint32_t* __restrict__ keys,
                                                uint32_t* __restrict__ imgHist) {
  __shared__ float lds[PB_ * 81];
  __shared__ float mArr[PB_], dArr[PB_];
  __shared__ uint32_t hcnt[CB_];
  int blk = blockIdx.x;
  int b = blk / IB_, lb = blk - b * IB_;
  int p0 = b * N_ + lb * PB_;
  int t = threadIdx.x;
  if (t < CB_) hcnt[t] = 0;
  const float4* src = (const float4*)(logits + (size_t)p0 * 81);
  for (int k = t; k < PB_ * 81 / 4; k += 256) ((float4*)lds)[k] = src[k];
  __syncthreads();
  if (t < PB_) {
    const float* lp = lds + t * 81;
    float m = lp[0];
    for (int i = 1; i <= C_; ++i) m = fmaxf(m, lp[i]);
    float denom = 0.f;
    for (int i = 0; i <= C_; ++i) denom += expf(lp[i] - m);
    mArr[t] = m; dArr[t] = denom;
  }
  __syncthreads();
#pragma unroll
  for (int iter = 0; iter < PB_ * C_ / 256; ++iter) {
    int e = iter * 256 + t;
    int pp = e / C_, c = e - pp * C_;
    float lv = lds[pp * 81 + c + 1];
    float score = expf(lv - mArr[pp]) / dArr[pp];
    uint32_t key = 0;
    if (score > 0.01f) {
      key = __float_as_uint(score);
      atomicAdd(&hcnt[(key >> 20) - 960], 1u);
    }
    keys[(size_t)p0 * C_ + e] = key;
  }
  __syncthreads();
  if (t < CB_ && hcnt[t]) atomicAdd(&imgHist[b * CB_ + t], hcnt[t]);
}

__global__ __launch_bounds__(256) void k_refine(const uint32_t* __restrict__ keys,
                                                const uint32_t* __restrict__ imgHist,
                                                uint32_t* __restrict__ fineHist) {
  __shared__ int s_cb;
  int blk = blockIdx.x;
  int b = blk / NBLK_, lb = blk - b * NBLK_;
  int t = threadIdx.x;
  if (t < 64) {
    uint32_t v = imgHist[b * CB_ + t];
#pragma unroll
    for (int d = 1; d < 64; d <<= 1) {
      uint32_t o = __shfl_down(v, d);
      v += (t + d < 64) ? o : 0;
    }
    uint32_t nxt = __shfl_down(v, 1);
    if (t == 63) nxt = 0;
    uint32_t total = __shfl(v, 0);
    if (t == 0 && total < KP_) s_cb = -1;
    if (total >= KP_ && v >= KP_ && nxt < KP_) s_cb = t;
  }
  __syncthreads();
  int cb = s_cb;
  if (cb < 0) return;
  int ti = lb * 256 + t;
  if (ti >= NC_ / 4) return;
  uint4 k4 = ((const uint4*)(keys + (size_t)b * NC_))[ti];
  uint32_t want = (uint32_t)(cb + 960);
  uint32_t kv[4] = {k4.x, k4.y, k4.z, k4.w};
#pragma unroll
  for (int q = 0; q < 4; ++q)
    if ((kv[q] >> 20) == want)
      atomicAdd(&fineHist[b * FB_ + ((kv[q] >> 13) & (FB_ - 1))], 1u);
}

__global__ __launch_bounds__(256) void k_compact(const uint32_t* __restrict__ keys,
                                                 const uint32_t* __restrict__ imgHist,
                                                 const uint32_t* __restrict__ fineHist,
                                                 uint32_t* __restrict__ cnt,
                                                 u64* __restrict__ cand) {
  __shared__ int s_cb;
  __shared__ uint32_t s_tail;
  __shared__ uint32_t s_thr;
  int blk = blockIdx.x;
  int b = blk / NBLK_, lb = blk - b * NBLK_;
  int t = threadIdx.x;
  if (t < 64) {
    uint32_t v = imgHist[b * CB_ + t];
#pragma unroll
    for (int d = 1; d < 64; d <<= 1) {
      uint32_t o = __shfl_down(v, d);
      v += (t + d < 64) ? o : 0;
    }
    uint32_t nxt = __shfl_down(v, 1);
    if (t == 63) nxt = 0;
    uint32_t total = __shfl(v, 0);
    if (t == 0 && total < KP_) { s_cb = -1; s_tail = 0; }
    if (total >= KP_ && v >= KP_ && nxt < KP_) { s_cb = t; s_tail = nxt; }
  }
  __syncthreads();
  int cb = s_cb;
  if (cb < 0) {
    if (t == 0) s_thr = 1u;
  } else if (t < 64) {
    uint32_t f0 = fineHist[b * FB_ + 2 * t];
    uint32_t f1 = fineHist[b * FB_ + 2 * t + 1];
    uint32_t v = f0 + f1;
#pragma unroll
    for (int d = 1; d < 64; d <<= 1) {
      uint32_t o = __shfl_down(v, d);
      v += (t + d < 64) ? o : 0;
    }
    uint32_t nxt = __shfl_down(v, 1);
    if (t == 63) nxt = 0;
    uint32_t tail = s_tail;
    bool c0 = (tail + v >= KP_);
    bool c1 = (tail + nxt + f1 >= KP_);
    bool cN = (tail + nxt >= KP_);
    if (c0 && !c1) s_thr = ((uint32_t)(cb + 960) << 20) | ((uint32_t)(2 * t) << 13);
    if (c1 && !cN) s_thr = ((uint32_t)(cb + 960) << 20) | ((uint32_t)(2 * t + 1) << 13);
  }
  __syncthreads();
  uint32_t thrb = s_thr;
  int ti = lb * 256 + t;
  if (ti >= NC_ / 4) return;
  uint4 k4 = ((const uint4*)(keys + (size_t)b * NC_))[ti];
  int slot = (ti >> 4) & (SLOTS_ - 1);
  uint32_t kv[4] = {k4.x, k4.y, k4.z, k4.w};
  int ns = 0;
#pragma unroll
  for (int q = 0; q < 4; ++q) ns += (kv[q] >= thrb) ? 1 : 0;
  if (ns == 0) return;
  uint32_t pos = atomicAdd(&cnt[(b * SLOTS_ + slot) * 16], (uint32_t)ns);
  u64* seg = cand + (size_t)b * CAND_ + slot * SLOTCAP_;
  uint32_t baseIdx = (uint32_t)(ti * 4);
#pragma unroll
  for (int q = 0; q < 4; ++q) {
    if (kv[q] >= thrb) {
      if (pos < SLOTCAP_)
        seg[pos] = ((u64)kv[q] << 32) | (uint32_t)(~(baseIdx + q));
      ++pos;
    }
  }
}

__global__ __launch_bounds__(256) void k_rank(const u64* __restrict__ cand,
                                              uint32_t* __restrict__ rankPart) {
  __shared__ u64 sh[RSL_];
  int blk = blockIdx.x;
  int b = blk / (RIB_ * RJS_);
  int rem = blk - b * (RIB_ * RJS_);
  int lb = rem / RJS_, js = rem - lb * RJS_;
  int t = threadIdx.x;
  const u64* cb2 = cand + (size_t)b * CAND_;
  if (t < RSL_ / 2)
    ((ulonglong2*)sh)[t] = ((const ulonglong2*)(cb2 + js * RSL_))[t];
  int base = lb * (RT_ * RI_) + t;
  u64 ki[RI_];
#pragma unroll
  for (int q = 0; q < RI_; ++q) ki[q] = cb2[base + q * RT_];
  __syncthreads();
  int cnt4[RI_] = {0, 0, 0, 0};
#pragma unroll 4
  for (int j2 = 0; j2 < RSL_ / 2; ++j2) {
    ulonglong2 v = ((const ulonglong2*)sh)[j2];
#pragma unroll
    for (int q = 0; q < RI_; ++q) {
      cnt4[q] += (v.x > ki[q]) ? 1 : 0;
      cnt4[q] += (v.y > ki[q]) ? 1 : 0;
    }
  }
  uint32_t* rp = rankPart + ((size_t)(b * RJS_ + js)) * CAND_ + base;
#pragma unroll
  for (int q = 0; q < RI_; ++q) rp[q * RT_] = (uint32_t)cnt4[q];
}

__global__ __launch_bounds__(256) void k_scatter(
    const u64* __restrict__ cand, const uint32_t* __restrict__ rankPart,
    const float* __restrict__ bbox, const float* __restrict__ props,
    float* __restrict__ topScore, int* __restrict__ topLabel,
    float* __restrict__ topBox, float* __restrict__ nmsBox) {
  int blk = blockIdx.x;
  int b = blk / IBK_, lb = blk - b * IBK_;
  int t = threadIdx.x;
  int i = lb * 256 + t;
  u64 ki = cand[(size_t)b * CAND_ + i];
  if (ki == 0ull) return;
  uint32_t r = 0;
#pragma unroll
  for (int js = 0; js < RJS_; ++js)
    r += rankPart[((size_t)(b * RJS_ + js)) * CAND_ + i];
  if (r >= KP_) return;
  uint32_t sbits = (uint32_t)(ki >> 32);
  uint32_t idx = ~((uint32_t)ki);
  int n = idx / C_, c = idx % C_;
  float4 pr4 = ((const float4*)props)[(size_t)b * N_ + n];
  float4 d = ((const float4*)(bbox + ((size_t)b * N_ + n) * ((C_ + 1) * 4)))[c + 1];
  float x1, y1, x2, y2;
  decode4(pr4, d, x1, y1, x2, y2);
  float off = (float)(c + 1) * 4096.0f;
  size_t o = (size_t)b * KP_ + (size_t)r;
  topScore[o] = __uint_as_float(sbits);
  topLabel[o] = c + 1;
  ((float4*)topBox)[o] = make_float4(x1, y1, x2, y2);
  ((float4*)nmsBox)[o] = make_float4(x1 + off, y1 + off, x2 + off, y2 + off);
}

__global__ __launch_bounds__(64) void k_supmat(const float* __restrict__ nmsBox,
                                               u64* __restrict__ sup) {
  int blk = blockIdx.x;
  int b = blk / 528, r = blk - b * 528;
  int ti = 0, rem = r;
  while (rem >= 32 - ti) { rem -= 32 - ti; ++ti; }
  int tj = ti + rem;
  __shared__ float4 shj[64];
  __shared__ float sha[64];
  int l = threadIdx.x;
  const float4* boxes = (const float4*)(nmsBox + (size_t)b * KP_ * 4);
  float4 bj0 = boxes[tj * 64 + l];
  shj[l] = bj0;
  sha[l] = fmaxf(bj0.z - bj0.x, 0.f) * fmaxf(bj0.w - bj0.y, 0.f);
  int i = ti * 64 + l;
  float4 bi = boxes[i];
  float areai = fmaxf(bi.z - bi.x, 0.f) * fmaxf(bi.w - bi.y, 0.f);
  __syncthreads();
  u64 bits = 0;
  for (int jj = 0; jj < 64; ++jj) {
    int j = tj * 64 + jj;
    if (j > i) {
      float4 bj = shj[jj];
      float ltx = fmaxf(bi.x, bj.x), lty = fmaxf(bi.y, bj.y);
      float rbx = fminf(bi.z, bj.z), rby = fminf(bi.w, bj.w);
      float iw = fmaxf(rbx - ltx, 0.f), ih = fmaxf(rby - lty, 0.f);
      float inter = iw * ih;
      float uni = areai + sha[jj] - inter;
      float iou = inter / fmaxf(uni, 1e-9f);
      if (iou > 0.5f) bits |= (1ull << jj);
    }
  }
  sup[((size_t)b * KP_ + i) * NW_ + tj] = bits;
}

__global__ __launch_bounds__(64) void k_nms_scan(const u64* __restrict__ sup,
                                                 const float* __restrict__ topScore,
                                                 const int* __restrict__ topLabel,
                                                 const float* __restrict__ topBox,
                                                 float* __restrict__ out) {
  int b = blockIdx.x, l = threadIdx.x;
  int h = l >> 5, w = l & 31;
  const u64* base = sup + (size_t)b * KP_ * NW_;
  const float* ts = topScore + (size_t)b * KP_;
  const int* tl = topLabel + (size_t)b * KP_;
  const float4* tb = (const float4*)(topBox + (size_t)b * KP_ * 4);
  unsigned m32 = 0;
#pragma unroll
  for (int j = 0; j < 8; ++j) {
    float4 s4 = ((const float4*)ts)[l * 8 + j];
    if (!(s4.x > 0.f)) m32 |= 1u << (4 * j + 0);
    if (!(s4.y > 0.f)) m32 |= 1u << (4 * j + 1);
    if (!(s4.z > 0.f)) m32 |= 1u << (4 * j + 2);
    if (!(s4.w > 0.f)) m32 |= 1u << (4 * j + 3);
  }
  u64 removed = ((u64)__shfl(m32, 2 * w + 1) << 32) | (u64)__shfl(m32, 2 * w);

  int outCount = 0;
  auto emitRow = [&](int row, bool kept) {
    if (l == (outCount & 63)) {
      float4 bx = tb[row];
      out[((size_t)b * DET_ + outCount) * 4 + 0] = bx.x;
      out[((size_t)b * DET_ + outCount) * 4 + 1] = bx.y;
      out[((size_t)b * DET_ + outCount) * 4 + 2] = bx.z;
      out[((size_t)b * DET_ + outCount) * 4 + 3] = bx.w;
      out[B_ * DET_ * 4 + (size_t)b * DET_ + outCount] = kept ? ts[row] : -1.0f;
      out[B_ * DET_ * 4 + B_ * DET_ + (size_t)b * DET_ + outCount] = (float)tl[row];
    }
    ++outCount;
  };

  u64 ra[32], rb[32];
  auto loadc = [&](u64* dst, int c) {
    const u64* p = base + ((size_t)c * 64 + h * 32) * NW_ + w;
#pragma unroll
    for (int k = 0; k < 32; ++k) dst[k] = p[(size_t)k * NW_];
  };
  auto chunk = [&](u64* cur, int c) -> bool {
    u64 rm = __shfl(removed, c);
    unsigned rml = (unsigned)rm, rmh = (unsigned)(rm >> 32);
#pragma unroll
    for (int k = 0; k < 32; ++k) {
      unsigned dlo = __builtin_amdgcn_readlane((unsigned)cur[k], c);
      unsigned dhi = __builtin_amdgcn_readlane((unsigned)(cur[k] >> 32), c);
      if (!((rml >> k) & 1u)) { rml |= dlo; rmh |= dhi; }
    }
#pragma unroll
    for (int k = 0; k < 32; ++k) {
      unsigned dlo = __builtin_amdgcn_readlane((unsigned)cur[k], 32 + c);
      unsigned dhi = __builtin_amdgcn_readlane((unsigned)(cur[k] >> 32), 32 + c);
      if (!((rmh >> k) & 1u)) { rml |= dlo; rmh |= dhi; }
    }
    u64 rmfull = ((u64)rmh << 32) | rml;
    u64 kb = ~rmfull;
    while (kb) {
      if (outCount >= DET_) return true;
      int k = __builtin_ctzll(kb);
      kb &= kb - 1;
      emitRow(c * 64 + k, true);
    }
    if (outCount >= DET_) return true;
    unsigned kmask = h ? ~rmh : ~rml;
    u64 acc = 0;
#pragma unroll
    for (int k = 0; k < 32; ++k)
      acc |= ((kmask >> k) & 1u) ? cur[k] : 0ull;
    acc |= __shfl_xor(acc, 32);
    removed = (l == c) ? rmfull : removed;
    if (l < 32 && l >= c) removed |= acc;
    return false;
  };

  bool done = false;
  loadc(ra, 0);
  for (int c = 0; c < NW_ && !done; c += 2) {
    if (c + 1 < NW_) loadc(rb, c + 1);
    done = chunk(ra, c);
    if (!done) {
      if (c + 2 < NW_) loadc(ra, c + 2);
      done = chunk(rb, c + 1);
    }
  }
  if (outCount < DET_) {
    for (int c2 = 0; c2 < NW_ && outCount < DET_; ++c2) {
      u64 rm = __shfl(removed, c2);
      while (rm && outCount < DET_) {
        int k = __builtin_ctzll(rm);
        rm &= rm - 1;
        emitRow(c2 * 64 + k, false);
      }
    }
  }
}

extern "C" void kernel_launch(void* const* d_in, const int* in_sizes, int n_in,
                              void* d_out, int out_size, void* d_ws, size_t ws_size,
                              hipStream_t stream) {
  const float* label_pre = (const float*)d_in[0];
  const float* bbox_pre = (const float*)d_in[1];
  const float* props = (const float*)d_in[2];
  float* out = (float*)d_out;

  char* ws = (char*)d_ws;
  size_t off = 0;
  auto alloc = [&](size_t bytes) -> void* {
    void* p = ws + off;
    off = (off + bytes + 255) & ~(size_t)255;
    return p;
  };

  uint32_t* keys = (uint32_t*)alloc((size_t)B_ * NC_ * 4);
  // ---- zero-init region: hists, cnt, cand, top arrays ----
  size_t zero_begin = off;
  uint32_t* imgHist = (uint32_t*)alloc((size_t)B_ * CB_ * 4);
  uint32_t* fineHist = (uint32_t*)alloc((size_t)B_ * FB_ * 4);
  uint32_t* cnt = (uint32_t*)alloc((size_t)B_ * SLOTS_ * 16 * 4);
  u64* cand = (u64*)alloc((size_t)B_ * CAND_ * 8);
  float* topScore = (float*)alloc((size_t)B_ * KP_ * 4);
  int* topLabel = (int*)alloc((size_t)B_ * KP_ * 4);
  float* topBox = (float*)alloc((size_t)B_ * KP_ * 16);
  float* nmsBox = (float*)alloc((size_t)B_ * KP_ * 16);
  size_t zero_end = off;
  // --------------------------------------------------------
  u64* sup = (u64*)alloc((size_t)B_ * KP_ * NW_ * 8);
  uint32_t* rankPart = (uint32_t*)alloc((size_t)B_ * RJS_ * CAND_ * 4);

  if (off > ws_size) return;  // workspace too small -> fail visibly

  uint4* zeroPtr = (uint4*)(ws + zero_begin);
  int zeroN4 = (int)((zero_end - zero_begin) / 16);

  void* kargs[] = {
      (void*)&label_pre, (void*)&bbox_pre, (void*)&props,
      (void*)&keys, (void*)&imgHist, (void*)&fineHist, (void*)&cnt,
      (void*)&cand, (void*)&topScore, (void*)&topLabel, (void*)&topBox,
      (void*)&nmsBox, (void*)&sup, (void*)&rankPart, (void*)&out,
      (void*)&zeroPtr, (void*)&zeroN4};
  hipError_t err = hipLaunchCooperativeKernel((const void*)k_mega, dim3(GB_),
                                              dim3(256), kargs, 0, stream);
  if (err != hipSuccess) {
    // fallback: proven 8-dispatch path
    hipMemsetAsync(ws + zero_begin, 0, zero_end - zero_begin, stream);
    k_scores<<<B_ * IB_, 256, 0, stream>>>(label_pre, keys, imgHist);
    k_refine<<<B_ * NBLK_, 256, 0, stream>>>(keys, imgHist, fineHist);
    k_compact<<<B_ * NBLK_, 256, 0, stream>>>(keys, imgHist, fineHist, cnt, cand);
    k_rank<<<B_ * RIB_ * RJS_, RT_, 0, stream>>>(cand, rankPart);
    k_scatter<<<B_ * IBK_, 256, 0, stream>>>(cand, rankPart, bbox_pre, props,
                                             topScore, topLabel, topBox, nmsBox);
    k_supmat<<<B_ * 528, 64, 0, stream>>>(nmsBox, sup);
    k_nms_scan<<<B_, 64, 0, stream>>>(sup, topScore, topLabel, topBox, out);
  }
}

// Round 5
// 316.814 us; speedup vs baseline: 1.7605x; 1.7605x over previous
//
#include <hip/hip_runtime.h>
#include <stdint.h>

#define B_ 8
#define N_ 4000
#define C_ 80
#define NC_ (N_ * C_)          // 320000 candidates per image
#define KP_ 2048               // K_PRE
#define CAND_ 4096             // compaction capacity = SLOTS_*SLOTCAP_
#define SLOTS_ 32
#define SLOTCAP_ 128
#define DET_ 100
#define NW_ 32                 // u64 words per NMS row (2048 bits)
#define CLIP_ 4.135166556742356f

#define PB_ 16                 // proposals per k_scores block (proven round-2 shape)
#define IB_ (N_ / PB_)         // 250 blocks per image
#define NBLK_ ((NC_ / 4 + 255) / 256)   // 313 per-image blocks for compact

// full-resolution histogram over (key>>13): score in (0.01,1) -> key>>13 in
// [123166, 130047]; bins [BINBASE_, BINBASE_+NBIN_) with BINBASE_=962<<7.
// Granularity == the old 2-level (coarse<<20 | fine<<13) scheme exactly, so
// the selected threshold bit-pattern is identical.
#define NBIN_ 6912             // = 256 threads * 27 bins
#define BINBASE_ 123136u       // 962<<7

#define RT_ 256                // threads per rank block
#define RI_ 4                  // i-keys per thread (amortize LDS broadcast 4x)
#define RJS_ 16                // j-slices
#define RSL_ (CAND_ / RJS_)    // 256 keys per slice
#define RIB_ (CAND_ / (RT_ * RI_))  // 4 i-blocks per image
#define RNB_ (RIB_ * RJS_)     // 64 rank blocks per image

typedef unsigned long long u64;

__device__ __forceinline__ void decode4(const float4 pr, const float4 d,
                                        float& x1, float& y1, float& x2, float& y2) {
  float w = pr.z - pr.x, h = pr.w - pr.y;
  float cx = pr.x + 0.5f * w, cy = pr.y + 0.5f * h;
  float dx = d.x / 10.0f, dy = d.y / 10.0f;
  float dw = fminf(d.z / 5.0f, CLIP_), dh = fminf(d.w / 5.0f, CLIP_);
  float pcx = dx * w + cx, pcy = dy * h + cy;
  float pw = expf(dw) * w, ph = expf(dh) * h;
  x1 = pcx - 0.5f * pw; y1 = pcy - 0.5f * ph;
  x2 = pcx + 0.5f * pw; y2 = pcy + 0.5f * ph;
}

// K1: FUSED softmax + scores + keys + DIRECT full-res global histogram.
// (k_refine eliminated: no coarse pass needed.) Also zero-inits cnt+cand
// for the next dispatch (grid-stride; replaces part of the memset).
// Softmax phase keeps the reference's exact sequential order (bit-exact).
__global__ __launch_bounds__(256) void k_scores(const float* __restrict__ logits,
                                                uint32_t* __restrict__ keys,
                                                uint32_t* __restrict__ fineHist,
                                                uint4* __restrict__ zcc, int zccN) {
  __shared__ float lds[PB_ * 81];
  __shared__ float mArr[PB_], dArr[PB_];
  int blk = blockIdx.x;                 // 0 .. B_*IB_-1
  int b = blk / IB_, lb = blk - b * IB_;
  int p0 = b * N_ + lb * PB_;           // global proposal base
  int t = threadIdx.x;
  // zero cnt+cand region (consumed by k_compact next dispatch)
  for (int i = blk * 256 + t; i < zccN; i += B_ * IB_ * 256)
    zcc[i] = make_uint4(0u, 0u, 0u, 0u);
  const float4* src = (const float4*)(logits + (size_t)p0 * 81);
  for (int k = t; k < PB_ * 81 / 4; k += 256) ((float4*)lds)[k] = src[k];
  __syncthreads();
  if (t < PB_) {
    const float* lp = lds + t * 81;
    float m = lp[0];
    for (int i = 1; i <= C_; ++i) m = fmaxf(m, lp[i]);
    float denom = 0.f;
    for (int i = 0; i <= C_; ++i) denom += expf(lp[i] - m);
    mArr[t] = m; dArr[t] = denom;
  }
  __syncthreads();
#pragma unroll
  for (int iter = 0; iter < PB_ * C_ / 256; ++iter) {   // 5 iters
    int e = iter * 256 + t;             // 0..1279
    int pp = e / C_, c = e - pp * C_;
    float lv = lds[pp * 81 + c + 1];
    float score = expf(lv - mArr[pp]) / dArr[pp];
    uint32_t key = 0;
    if (score > 0.01f) {
      key = __float_as_uint(score);
      atomicAdd(&fineHist[b * NBIN_ + ((key >> 13) - BINBASE_)], 1u);
    }
    keys[(size_t)p0 * C_ + e] = key;                    // coalesced
  }
}

// K2: inline full-res threshold scan + compact survivors into 32 slots/image.
// The scan (27 bins/thread + wave shfl suffix scan + wave-total combine) is
// deterministic and identical across all blocks of an image; thr bit-pattern
// equals the old coarse+fine scheme exactly. Also zero-inits the top arrays
// (sentinel slots for the rank/scatter stage).
__global__ __launch_bounds__(256) void k_compact(const uint32_t* __restrict__ keys,
                                                 const uint32_t* __restrict__ fineHist,
                                                 uint32_t* __restrict__ cnt,
                                                 u64* __restrict__ cand,
                                                 uint4* __restrict__ ztop, int ztopN) {
  __shared__ uint32_t wtot[4];
  __shared__ uint32_t s_thr;
  int blk = blockIdx.x;
  int b = blk / NBLK_, lb = blk - b * NBLK_;
  int t = threadIdx.x;
  int lane = t & 63, wv = t >> 6;
  // zero top arrays (consumed by k_rank's finisher next dispatch)
  for (int i = blk * 256 + t; i < ztopN; i += B_ * NBLK_ * 256)
    ztop[i] = make_uint4(0u, 0u, 0u, 0u);
  // ---- threshold scan over 6912 bins ----
  const uint32_t* fh = fineHist + b * NBIN_ + t * 27;
  uint32_t csum = 0;
#pragma unroll
  for (int j = 0; j < 27; ++j) csum += fh[j];
  uint32_t v = csum;
#pragma unroll
  for (int d = 1; d < 64; d <<= 1) {                    // wave inclusive suffix scan
    uint32_t o = __shfl_down(v, d);
    v += (lane + d < 64) ? o : 0;
  }
  if (lane == 0) wtot[wv] = v;                          // wave total
  __syncthreads();
  uint32_t hi = 0;
  for (int w2 = wv + 1; w2 < 4; ++w2) hi += wtot[w2];
  uint32_t suffInc = v + hi;                            // keys in chunks >= t
  uint32_t suffExc = suffInc - csum;                    // keys in chunks >  t
  uint32_t total = wtot[0] + wtot[1] + wtot[2] + wtot[3];
  if (t == 0 && total < KP_) s_thr = 1u;                // pass all nonzero keys
  if (total >= KP_ && suffInc >= KP_ && suffExc < KP_) {
    uint32_t running = suffExc;
    for (int j = 26; j >= 0; --j) {
      running += fh[j];
      if (running >= KP_) {
        s_thr = (BINBASE_ + (uint32_t)t * 27u + (uint32_t)j) << 13;
        break;
      }
    }
  }
  __syncthreads();
  uint32_t thrb = s_thr;
  // ---- compaction (unchanged) ----
  int ti = lb * 256 + t;
  if (ti >= NC_ / 4) return;
  uint4 k4 = ((const uint4*)(keys + (size_t)b * NC_))[ti];
  int slot = (ti >> 4) & (SLOTS_ - 1);
  uint32_t kv[4] = {k4.x, k4.y, k4.z, k4.w};
  int ns = 0;
#pragma unroll
  for (int q = 0; q < 4; ++q) ns += (kv[q] >= thrb) ? 1 : 0;
  if (ns == 0) return;
  uint32_t pos = atomicAdd(&cnt[(b * SLOTS_ + slot) * 16], (uint32_t)ns);
  u64* seg = cand + (size_t)b * CAND_ + slot * SLOTCAP_;
  uint32_t baseIdx = (uint32_t)(ti * 4);
#pragma unroll
  for (int q = 0; q < 4; ++q) {
    if (kv[q] >= thrb) {
      if (pos < SLOTCAP_)
        seg[pos] = ((u64)kv[q] << 32) | (uint32_t)(~(baseIdx + q));
      ++pos;
    }
  }
}

// K3: i-blocked j-split rank + FUSED scatter via last-block-per-image handoff.
// Each of the 64 blocks/image writes its partial counts (plain stores,
// disjoint regions), then threadfence + ticket atomicAdd; the 64th block
// acquires, sums the 16 partials per candidate, decodes, and scatters —
// replacing the k_scatter dispatch. No grid-wide sync anywhere.
__global__ __launch_bounds__(256) void k_rank(
    const u64* __restrict__ cand, uint32_t* __restrict__ rankPart,
    uint32_t* __restrict__ ticket,
    const float* __restrict__ bbox, const float* __restrict__ props,
    float* __restrict__ topScore, int* __restrict__ topLabel,
    float* __restrict__ topBox, float* __restrict__ nmsBox) {
  __shared__ u64 sh[RSL_];
  __shared__ uint32_t s_old;
  int blk = blockIdx.x;                  // b * RNB_ + lb * RJS_ + js
  int b = blk / RNB_;
  int rem = blk - b * RNB_;
  int lb = rem / RJS_, js = rem - lb * RJS_;
  int t = threadIdx.x;
  const u64* cb2 = cand + (size_t)b * CAND_;
  if (t < RSL_ / 2)
    ((ulonglong2*)sh)[t] = ((const ulonglong2*)(cb2 + js * RSL_))[t];
  int base = lb * (RT_ * RI_) + t;
  u64 ki[RI_];
#pragma unroll
  for (int q = 0; q < RI_; ++q) ki[q] = cb2[base + q * RT_];   // coalesced
  __syncthreads();
  int cnt4[RI_] = {0, 0, 0, 0};
#pragma unroll 4
  for (int j2 = 0; j2 < RSL_ / 2; ++j2) {  // 128 uniform ds_read_b128
    ulonglong2 v = ((const ulonglong2*)sh)[j2];
#pragma unroll
    for (int q = 0; q < RI_; ++q) {
      cnt4[q] += (v.x > ki[q]) ? 1 : 0;
      cnt4[q] += (v.y > ki[q]) ? 1 : 0;
    }
  }
  uint32_t* rp = rankPart + ((size_t)(b * RJS_ + js)) * CAND_ + base;
#pragma unroll
  for (int q = 0; q < RI_; ++q) rp[q * RT_] = (uint32_t)cnt4[q];  // coalesced

  // ---- last-block handoff: fused scatter ----
  __threadfence();                       // release this block's partials
  __syncthreads();
  if (t == 0) s_old = atomicAdd(&ticket[b], 1u);
  __syncthreads();
  if (s_old == RNB_ - 1) {
    __threadfence();                     // acquire all blocks' partials
    for (int i = t; i < CAND_; i += RT_) {
      u64 kk = cb2[i];
      if (kk == 0ull) continue;
      uint32_t r = 0;
#pragma unroll
      for (int js2 = 0; js2 < RJS_; ++js2)
        r += rankPart[((size_t)(b * RJS_ + js2)) * CAND_ + i];
      if (r >= KP_) continue;
      uint32_t sbits = (uint32_t)(kk >> 32);
      uint32_t idx = ~((uint32_t)kk);
      int n = idx / C_, c = idx % C_;
      float4 pr4 = ((const float4*)props)[(size_t)b * N_ + n];
      float4 d = ((const float4*)(bbox + ((size_t)b * N_ + n) * ((C_ + 1) * 4)))[c + 1];
      float x1, y1, x2, y2;
      decode4(pr4, d, x1, y1, x2, y2);
      float off = (float)(c + 1) * 4096.0f;
      size_t o = (size_t)b * KP_ + (size_t)r;
      topScore[o] = __uint_as_float(sbits);
      topLabel[o] = c + 1;
      ((float4*)topBox)[o] = make_float4(x1, y1, x2, y2);
      ((float4*)nmsBox)[o] = make_float4(x1 + off, y1 + off, x2 + off, y2 + off);
    }
  }
}

// K4: suppression bitmatrix — triangular grid (528 tiles/image), j-boxes and
// areaj in LDS. Only tj >= ti tiles written; downstream never reads w < chunk.
__global__ __launch_bounds__(64) void k_supmat(const float* __restrict__ nmsBox,
                                               u64* __restrict__ sup) {
  int blk = blockIdx.x;
  int b = blk / 528, r = blk - b * 528;
  int ti = 0, rem = r;
  while (rem >= 32 - ti) { rem -= 32 - ti; ++ti; }
  int tj = ti + rem;
  __shared__ float4 shj[64];
  __shared__ float sha[64];
  int l = threadIdx.x;
  const float4* boxes = (const float4*)(nmsBox + (size_t)b * KP_ * 4);
  float4 bj0 = boxes[tj * 64 + l];
  shj[l] = bj0;
  sha[l] = fmaxf(bj0.z - bj0.x, 0.f) * fmaxf(bj0.w - bj0.y, 0.f);
  int i = ti * 64 + l;
  float4 bi = boxes[i];
  float areai = fmaxf(bi.z - bi.x, 0.f) * fmaxf(bi.w - bi.y, 0.f);
  __syncthreads();
  u64 bits = 0;
  for (int jj = 0; jj < 64; ++jj) {
    int j = tj * 64 + jj;
    if (j > i) {
      float4 bj = shj[jj];
      float ltx = fmaxf(bi.x, bj.x), lty = fmaxf(bi.y, bj.y);
      float rbx = fminf(bi.z, bj.z), rby = fminf(bi.w, bj.w);
      float iw = fmaxf(rbx - ltx, 0.f), ih = fmaxf(rby - lty, 0.f);
      float inter = iw * ih;
      float uni = areai + sha[jj] - inter;
      float iou = inter / fmaxf(uni, 1e-9f);
      if (iou > 0.5f) bits |= (1ull << jj);
    }
  }
  sup[((size_t)b * KP_ + i) * NW_ + tj] = bits;
}

// K5: chunked greedy NMS with early exit + direct output emission.
__global__ __launch_bounds__(64) void k_nms_scan(const u64* __restrict__ sup,
                                                 const float* __restrict__ topScore,
                                                 const int* __restrict__ topLabel,
                                                 const float* __restrict__ topBox,
                                                 float* __restrict__ out) {
  int b = blockIdx.x, l = threadIdx.x;
  int h = l >> 5, w = l & 31;
  const u64* base = sup + (size_t)b * KP_ * NW_;
  const float* ts = topScore + (size_t)b * KP_;
  const int* tl = topLabel + (size_t)b * KP_;
  const float4* tb = (const float4*)(topBox + (size_t)b * KP_ * 4);
  unsigned m32 = 0;
#pragma unroll
  for (int j = 0; j < 8; ++j) {
    float4 s4 = ((const float4*)ts)[l * 8 + j];
    if (!(s4.x > 0.f)) m32 |= 1u << (4 * j + 0);
    if (!(s4.y > 0.f)) m32 |= 1u << (4 * j + 1);
    if (!(s4.z > 0.f)) m32 |= 1u << (4 * j + 2);
    if (!(s4.w > 0.f)) m32 |= 1u << (4 * j + 3);
  }
  u64 removed = ((u64)__shfl(m32, 2 * w + 1) << 32) | (u64)__shfl(m32, 2 * w);

  int outCount = 0;                                  // wave-uniform
  auto emitRow = [&](int row, bool kept) {
    if (l == (outCount & 63)) {
      float4 bx = tb[row];
      out[((size_t)b * DET_ + outCount) * 4 + 0] = bx.x;
      out[((size_t)b * DET_ + outCount) * 4 + 1] = bx.y;
      out[((size_t)b * DET_ + outCount) * 4 + 2] = bx.z;
      out[((size_t)b * DET_ + outCount) * 4 + 3] = bx.w;
      out[B_ * DET_ * 4 + (size_t)b * DET_ + outCount] = kept ? ts[row] : -1.0f;
      out[B_ * DET_ * 4 + B_ * DET_ + (size_t)b * DET_ + outCount] = (float)tl[row];
    }
    ++outCount;
  };

  u64 ra[32], rb[32];
  auto loadc = [&](u64* dst, int c) {
    const u64* p = base + ((size_t)c * 64 + h * 32) * NW_ + w;
#pragma unroll
    for (int k = 0; k < 32; ++k) dst[k] = p[(size_t)k * NW_];
  };
  auto chunk = [&](u64* cur, int c) -> bool {        // returns done
    u64 rm = __shfl(removed, c);
    unsigned rml = (unsigned)rm, rmh = (unsigned)(rm >> 32);
#pragma unroll
    for (int k = 0; k < 32; ++k) {
      unsigned dlo = __builtin_amdgcn_readlane((unsigned)cur[k], c);
      unsigned dhi = __builtin_amdgcn_readlane((unsigned)(cur[k] >> 32), c);
      if (!((rml >> k) & 1u)) { rml |= dlo; rmh |= dhi; }
    }
#pragma unroll
    for (int k = 0; k < 32; ++k) {
      unsigned dlo = __builtin_amdgcn_readlane((unsigned)cur[k], 32 + c);
      unsigned dhi = __builtin_amdgcn_readlane((unsigned)(cur[k] >> 32), 32 + c);
      if (!((rmh >> k) & 1u)) { rml |= dlo; rmh |= dhi; }
    }
    u64 rmfull = ((u64)rmh << 32) | rml;
    u64 kb = ~rmfull;
    while (kb) {
      if (outCount >= DET_) return true;
      int k = __builtin_ctzll(kb);
      kb &= kb - 1;
      emitRow(c * 64 + k, true);
    }
    if (outCount >= DET_) return true;
    unsigned kmask = h ? ~rmh : ~rml;
    u64 acc = 0;
#pragma unroll
    for (int k = 0; k < 32; ++k)
      acc |= ((kmask >> k) & 1u) ? cur[k] : 0ull;
    acc |= __shfl_xor(acc, 32);
    removed = (l == c) ? rmfull : removed;
    if (l < 32 && l >= c) removed |= acc;
    return false;
  };

  bool done = false;
  loadc(ra, 0);
  for (int c = 0; c < NW_ && !done; c += 2) {
    if (c + 1 < NW_) loadc(rb, c + 1);
    done = chunk(ra, c);
    if (!done) {
      if (c + 2 < NW_) loadc(ra, c + 2);
      done = chunk(rb, c + 1);
    }
  }
  if (outCount < DET_) {
    for (int c2 = 0; c2 < NW_ && outCount < DET_; ++c2) {
      u64 rm = __shfl(removed, c2);
      while (rm && outCount < DET_) {
        int k = __builtin_ctzll(rm);
        rm &= rm - 1;
        emitRow(c2 * 64 + k, false);
      }
    }
  }
}

extern "C" void kernel_launch(void* const* d_in, const int* in_sizes, int n_in,
                              void* d_out, int out_size, void* d_ws, size_t ws_size,
                              hipStream_t stream) {
  const float* label_pre = (const float*)d_in[0];
  const float* bbox_pre = (const float*)d_in[1];
  const float* props = (const float*)d_in[2];
  float* out = (float*)d_out;

  char* ws = (char*)d_ws;
  size_t off = 0;
  auto alloc = [&](size_t bytes) -> void* {
    void* p = ws + off;
    off = (off + bytes + 255) & ~(size_t)255;
    return p;
  };

  uint32_t* keys = (uint32_t*)alloc((size_t)B_ * NC_ * 4);
  // ---- memset region: fineHist + tickets only (~221 KB) ----
  size_t zero_begin = off;
  uint32_t* fineHist = (uint32_t*)alloc((size_t)B_ * NBIN_ * 4);
  uint32_t* ticket = (uint32_t*)alloc((size_t)B_ * 4);
  size_t zero_end = off;
  // ---- zeroed by k_scores (cnt+cand contiguous) ----
  uint32_t* cnt = (uint32_t*)alloc((size_t)B_ * SLOTS_ * 16 * 4);   // 16384 B
  u64* cand = (u64*)alloc((size_t)B_ * CAND_ * 8);                  // 262144 B
  // ---- zeroed by k_compact (top arrays contiguous) ----
  float* topScore = (float*)alloc((size_t)B_ * KP_ * 4);            // 65536 B
  int* topLabel = (int*)alloc((size_t)B_ * KP_ * 4);                // 65536 B
  float* topBox = (float*)alloc((size_t)B_ * KP_ * 16);             // 524288 B
  float* nmsBox = (float*)alloc((size_t)B_ * KP_ * 16);             // 524288 B
  // ---- no zeroing needed ----
  u64* sup = (u64*)alloc((size_t)B_ * KP_ * NW_ * 8);
  uint32_t* rankPart = (uint32_t*)alloc((size_t)B_ * RJS_ * CAND_ * 4);

  if (off > ws_size) return;  // workspace too small -> fail visibly

  uint4* zcc = (uint4*)cnt;
  int zccN = (int)(((size_t)B_ * SLOTS_ * 16 * 4 + (size_t)B_ * CAND_ * 8) / 16);   // 17408
  uint4* ztop = (uint4*)topScore;
  int ztopN = (int)(((size_t)B_ * KP_ * 4 * 2 + (size_t)B_ * KP_ * 16 * 2) / 16);   // 73728

  hipMemsetAsync(ws + zero_begin, 0, zero_end - zero_begin, stream);

  k_scores<<<B_ * IB_, 256, 0, stream>>>(label_pre, keys, fineHist, zcc, zccN);
  k_compact<<<B_ * NBLK_, 256, 0, stream>>>(keys, fineHist, cnt, cand, ztop, ztopN);
  k_rank<<<B_ * RNB_, RT_, 0, stream>>>(cand, rankPart, ticket, bbox_pre, props,
                                        topScore, topLabel, topBox, nmsBox);
  k_supmat<<<B_ * 528, 64, 0, stream>>>(nmsBox, sup);
  k_nms_scan<<<B_, 64, 0, stream>>>(sup, topScore, topLabel, topBox, out);
}

// Round 6
// 238.600 us; speedup vs baseline: 2.3375x; 1.3278x over previous
//
#include <hip/hip_runtime.h>
#include <stdint.h>

#define B_ 8
#define N_ 4000
#define C_ 80
#define NC_ (N_ * C_)          // 320000 candidates per image
#define KP_ 2048               // K_PRE
#define CAND_ 4096             // compaction capacity = SLOTS_*SLOTCAP_
#define SLOTS_ 32
#define SLOTCAP_ 128
#define DET_ 100
#define NW_ 32                 // u64 words per NMS row (2048 bits)
#define CLIP_ 4.135166556742356f

#define PB_ 16                 // proposals per k_scores block (proven round-2 shape)
#define IB_ (N_ / PB_)         // 250 blocks per image
#define NBLK_ ((NC_ / 4 + 255) / 256)   // 313 per-image blocks for compact

// full-resolution histogram over (key>>13): score in (0.01,1) -> key>>13 in
// [123166, 130047]; bins [BINBASE_, BINBASE_+NBIN_). Threshold bit-pattern
// identical to the original 2-level (coarse<<20 | fine<<13) scheme.
#define NBIN_ 6912             // = 256 threads * 27 bins
#define BINBASE_ 123136u       // 962<<7

#define RT_ 256                // threads per rank block
#define RI_ 4                  // i-keys per thread (amortize LDS broadcast 4x)
#define RJS_ 16                // j-slices
#define RSL_ (CAND_ / RJS_)    // 256 keys per slice
#define RIB_ (CAND_ / (RT_ * RI_))  // 4 i-blocks per image
#define IBK_ (CAND_ / 256)     // 16 scatter blocks per image

typedef unsigned long long u64;

__device__ __forceinline__ void decode4(const float4 pr, const float4 d,
                                        float& x1, float& y1, float& x2, float& y2) {
  float w = pr.z - pr.x, h = pr.w - pr.y;
  float cx = pr.x + 0.5f * w, cy = pr.y + 0.5f * h;
  float dx = d.x / 10.0f, dy = d.y / 10.0f;
  float dw = fminf(d.z / 5.0f, CLIP_), dh = fminf(d.w / 5.0f, CLIP_);
  float pcx = dx * w + cx, pcy = dy * h + cy;
  float pw = expf(dw) * w, ph = expf(dh) * h;
  x1 = pcx - 0.5f * pw; y1 = pcy - 0.5f * ph;
  x2 = pcx + 0.5f * pw; y2 = pcy + 0.5f * ph;
}

// K1: FUSED softmax + scores + keys + DIRECT full-res global histogram
// (refine pass eliminated). Also zero-inits cnt+cand for the next dispatch.
// Softmax keeps the reference's exact sequential order (bit-exact).
// ROUND-5 LESSON kept out of here: no device-scope fences anywhere.
__global__ __launch_bounds__(256) void k_scores(const float* __restrict__ logits,
                                                uint32_t* __restrict__ keys,
                                                uint32_t* __restrict__ fineHist,
                                                uint4* __restrict__ zcc, int zccN) {
  __shared__ float lds[PB_ * 81];
  __shared__ float mArr[PB_], dArr[PB_];
  int blk = blockIdx.x;                 // 0 .. B_*IB_-1
  int b = blk / IB_, lb = blk - b * IB_;
  int p0 = b * N_ + lb * PB_;           // global proposal base
  int t = threadIdx.x;
  // zero cnt+cand region (consumed by k_compact next dispatch)
  for (int i = blk * 256 + t; i < zccN; i += B_ * IB_ * 256)
    zcc[i] = make_uint4(0u, 0u, 0u, 0u);
  const float4* src = (const float4*)(logits + (size_t)p0 * 81);
  for (int k = t; k < PB_ * 81 / 4; k += 256) ((float4*)lds)[k] = src[k];
  __syncthreads();
  if (t < PB_) {
    const float* lp = lds + t * 81;
    float m = lp[0];
    for (int i = 1; i <= C_; ++i) m = fmaxf(m, lp[i]);
    float denom = 0.f;
    for (int i = 0; i <= C_; ++i) denom += expf(lp[i] - m);
    mArr[t] = m; dArr[t] = denom;
  }
  __syncthreads();
#pragma unroll
  for (int iter = 0; iter < PB_ * C_ / 256; ++iter) {   // 5 iters
    int e = iter * 256 + t;             // 0..1279
    int pp = e / C_, c = e - pp * C_;
    float lv = lds[pp * 81 + c + 1];
    float score = expf(lv - mArr[pp]) / dArr[pp];
    uint32_t key = 0;
    if (score > 0.01f) {
      key = __float_as_uint(score);
      atomicAdd(&fineHist[b * NBIN_ + ((key >> 13) - BINBASE_)], 1u);
    }
    keys[(size_t)p0 * C_ + e] = key;                    // coalesced
  }
}

// K2: inline full-res threshold scan + compact survivors into 32 slots/image.
// Scan (27 bins/thread + wave shfl suffix scan) is deterministic and
// identical across all blocks of an image. Also zero-inits the top arrays.
__global__ __launch_bounds__(256) void k_compact(const uint32_t* __restrict__ keys,
                                                 const uint32_t* __restrict__ fineHist,
                                                 uint32_t* __restrict__ cnt,
                                                 u64* __restrict__ cand,
                                                 uint4* __restrict__ ztop, int ztopN) {
  __shared__ uint32_t wtot[4];
  __shared__ uint32_t s_thr;
  int blk = blockIdx.x;
  int b = blk / NBLK_, lb = blk - b * NBLK_;
  int t = threadIdx.x;
  int lane = t & 63, wv = t >> 6;
  // zero top arrays (consumed by k_scatter, next+1 dispatch)
  for (int i = blk * 256 + t; i < ztopN; i += B_ * NBLK_ * 256)
    ztop[i] = make_uint4(0u, 0u, 0u, 0u);
  // ---- threshold scan over 6912 bins ----
  const uint32_t* fh = fineHist + b * NBIN_ + t * 27;
  uint32_t csum = 0;
#pragma unroll
  for (int j = 0; j < 27; ++j) csum += fh[j];
  uint32_t v = csum;
#pragma unroll
  for (int d = 1; d < 64; d <<= 1) {                    // wave inclusive suffix scan
    uint32_t o = __shfl_down(v, d);
    v += (lane + d < 64) ? o : 0;
  }
  if (lane == 0) wtot[wv] = v;                          // wave total
  __syncthreads();
  uint32_t hi = 0;
  for (int w2 = wv + 1; w2 < 4; ++w2) hi += wtot[w2];
  uint32_t suffInc = v + hi;                            // keys in chunks >= t
  uint32_t suffExc = suffInc - csum;                    // keys in chunks >  t
  uint32_t total = wtot[0] + wtot[1] + wtot[2] + wtot[3];
  if (t == 0 && total < KP_) s_thr = 1u;                // pass all nonzero keys
  if (total >= KP_ && suffInc >= KP_ && suffExc < KP_) {
    uint32_t running = suffExc;
    for (int j = 26; j >= 0; --j) {
      running += fh[j];
      if (running >= KP_) {
        s_thr = (BINBASE_ + (uint32_t)t * 27u + (uint32_t)j) << 13;
        break;
      }
    }
  }
  __syncthreads();
  uint32_t thrb = s_thr;
  // ---- compaction ----
  int ti = lb * 256 + t;
  if (ti >= NC_ / 4) return;
  uint4 k4 = ((const uint4*)(keys + (size_t)b * NC_))[ti];
  int slot = (ti >> 4) & (SLOTS_ - 1);
  uint32_t kv[4] = {k4.x, k4.y, k4.z, k4.w};
  int ns = 0;
#pragma unroll
  for (int q = 0; q < 4; ++q) ns += (kv[q] >= thrb) ? 1 : 0;
  if (ns == 0) return;
  uint32_t pos = atomicAdd(&cnt[(b * SLOTS_ + slot) * 16], (uint32_t)ns);
  u64* seg = cand + (size_t)b * CAND_ + slot * SLOTCAP_;
  uint32_t baseIdx = (uint32_t)(ti * 4);
#pragma unroll
  for (int q = 0; q < 4; ++q) {
    if (kv[q] >= thrb) {
      if (pos < SLOTCAP_)
        seg[pos] = ((u64)kv[q] << 32) | (uint32_t)(~(baseIdx + q));
      ++pos;
    }
  }
}

// K3: i-blocked j-split rank — plain partial writes only. ROUND-5 LESSON:
// the last-block fused scatter cost ~90us (__threadfence per block = per-XCD
// L2 writeback x 512). Separate k_scatter dispatch costs ~8us total instead.
__global__ __launch_bounds__(256) void k_rank(const u64* __restrict__ cand,
                                              uint32_t* __restrict__ rankPart) {
  __shared__ u64 sh[RSL_];
  int blk = blockIdx.x;                  // b * (RIB_*RJS_) + lb * RJS_ + js
  int b = blk / (RIB_ * RJS_);
  int rem = blk - b * (RIB_ * RJS_);
  int lb = rem / RJS_, js = rem - lb * RJS_;
  int t = threadIdx.x;
  const u64* cb2 = cand + (size_t)b * CAND_;
  if (t < RSL_ / 2)
    ((ulonglong2*)sh)[t] = ((const ulonglong2*)(cb2 + js * RSL_))[t];
  int base = lb * (RT_ * RI_) + t;
  u64 ki[RI_];
#pragma unroll
  for (int q = 0; q < RI_; ++q) ki[q] = cb2[base + q * RT_];   // coalesced
  __syncthreads();
  int cnt4[RI_] = {0, 0, 0, 0};
#pragma unroll 4
  for (int j2 = 0; j2 < RSL_ / 2; ++j2) {  // 128 uniform ds_read_b128
    ulonglong2 v = ((const ulonglong2*)sh)[j2];
#pragma unroll
    for (int q = 0; q < RI_; ++q) {
      cnt4[q] += (v.x > ki[q]) ? 1 : 0;
      cnt4[q] += (v.y > ki[q]) ? 1 : 0;
    }
  }
  uint32_t* rp = rankPart + ((size_t)(b * RJS_ + js)) * CAND_ + base;
#pragma unroll
  for (int q = 0; q < RI_; ++q) rp[q * RT_] = (uint32_t)cnt4[q];  // coalesced
}

// K4: sum the RJS_ partial ranks (L2-hot) and scatter: decode + write top
// arrays at position rank. Sentinel slots keep the zero-init (score 0.0
// behaves exactly like -1.0 downstream).
__global__ __launch_bounds__(256) void k_scatter(
    const u64* __restrict__ cand, const uint32_t* __restrict__ rankPart,
    const float* __restrict__ bbox, const float* __restrict__ props,
    float* __restrict__ topScore, int* __restrict__ topLabel,
    float* __restrict__ topBox, float* __restrict__ nmsBox) {
  int blk = blockIdx.x;                  // B_ * IBK_
  int b = blk / IBK_, lb = blk - b * IBK_;
  int t = threadIdx.x;
  int i = lb * 256 + t;
  u64 ki = cand[(size_t)b * CAND_ + i];
  if (ki == 0ull) return;
  uint32_t r = 0;
#pragma unroll
  for (int js = 0; js < RJS_; ++js)
    r += rankPart[((size_t)(b * RJS_ + js)) * CAND_ + i];
  if (r >= KP_) return;
  uint32_t sbits = (uint32_t)(ki >> 32);
  uint32_t idx = ~((uint32_t)ki);
  int n = idx / C_, c = idx % C_;
  float4 pr4 = ((const float4*)props)[(size_t)b * N_ + n];
  float4 d = ((const float4*)(bbox + ((size_t)b * N_ + n) * ((C_ + 1) * 4)))[c + 1];
  float x1, y1, x2, y2;
  decode4(pr4, d, x1, y1, x2, y2);
  float off = (float)(c + 1) * 4096.0f;
  size_t o = (size_t)b * KP_ + (size_t)r;
  topScore[o] = __uint_as_float(sbits);
  topLabel[o] = c + 1;
  ((float4*)topBox)[o] = make_float4(x1, y1, x2, y2);
  ((float4*)nmsBox)[o] = make_float4(x1 + off, y1 + off, x2 + off, y2 + off);
}

// K5: suppression bitmatrix — triangular grid (528 tiles/image), j-boxes and
// areaj in LDS. Only tj >= ti tiles written; downstream never reads w < chunk.
__global__ __launch_bounds__(64) void k_supmat(const float* __restrict__ nmsBox,
                                               u64* __restrict__ sup) {
  int blk = blockIdx.x;
  int b = blk / 528, r = blk - b * 528;
  int ti = 0, rem = r;
  while (rem >= 32 - ti) { rem -= 32 - ti; ++ti; }
  int tj = ti + rem;
  __shared__ float4 shj[64];
  __shared__ float sha[64];
  int l = threadIdx.x;
  const float4* boxes = (const float4*)(nmsBox + (size_t)b * KP_ * 4);
  float4 bj0 = boxes[tj * 64 + l];
  shj[l] = bj0;
  sha[l] = fmaxf(bj0.z - bj0.x, 0.f) * fmaxf(bj0.w - bj0.y, 0.f);
  int i = ti * 64 + l;
  float4 bi = boxes[i];
  float areai = fmaxf(bi.z - bi.x, 0.f) * fmaxf(bi.w - bi.y, 0.f);
  __syncthreads();
  u64 bits = 0;
  for (int jj = 0; jj < 64; ++jj) {
    int j = tj * 64 + jj;
    if (j > i) {
      float4 bj = shj[jj];
      float ltx = fmaxf(bi.x, bj.x), lty = fmaxf(bi.y, bj.y);
      float rbx = fminf(bi.z, bj.z), rby = fminf(bi.w, bj.w);
      float iw = fmaxf(rbx - ltx, 0.f), ih = fmaxf(rby - lty, 0.f);
      float inter = iw * ih;
      float uni = areai + sha[jj] - inter;
      float iou = inter / fmaxf(uni, 1e-9f);
      if (iou > 0.5f) bits |= (1ull << jj);
    }
  }
  sup[((size_t)b * KP_ + i) * NW_ + tj] = bits;
}

// K6: chunked greedy NMS with early exit + direct output emission.
__global__ __launch_bounds__(64) void k_nms_scan(const u64* __restrict__ sup,
                                                 const float* __restrict__ topScore,
                                                 const int* __restrict__ topLabel,
                                                 const float* __restrict__ topBox,
                                                 float* __restrict__ out) {
  int b = blockIdx.x, l = threadIdx.x;
  int h = l >> 5, w = l & 31;
  const u64* base = sup + (size_t)b * KP_ * NW_;
  const float* ts = topScore + (size_t)b * KP_;
  const int* tl = topLabel + (size_t)b * KP_;
  const float4* tb = (const float4*)(topBox + (size_t)b * KP_ * 4);
  unsigned m32 = 0;
#pragma unroll
  for (int j = 0; j < 8; ++j) {
    float4 s4 = ((const float4*)ts)[l * 8 + j];
    if (!(s4.x > 0.f)) m32 |= 1u << (4 * j + 0);
    if (!(s4.y > 0.f)) m32 |= 1u << (4 * j + 1);
    if (!(s4.z > 0.f)) m32 |= 1u << (4 * j + 2);
    if (!(s4.w > 0.f)) m32 |= 1u << (4 * j + 3);
  }
  u64 removed = ((u64)__shfl(m32, 2 * w + 1) << 32) | (u64)__shfl(m32, 2 * w);

  int outCount = 0;                                  // wave-uniform
  auto emitRow = [&](int row, bool kept) {
    if (l == (outCount & 63)) {
      float4 bx = tb[row];
      out[((size_t)b * DET_ + outCount) * 4 + 0] = bx.x;
      out[((size_t)b * DET_ + outCount) * 4 + 1] = bx.y;
      out[((size_t)b * DET_ + outCount) * 4 + 2] = bx.z;
      out[((size_t)b * DET_ + outCount) * 4 + 3] = bx.w;
      out[B_ * DET_ * 4 + (size_t)b * DET_ + outCount] = kept ? ts[row] : -1.0f;
      out[B_ * DET_ * 4 + B_ * DET_ + (size_t)b * DET_ + outCount] = (float)tl[row];
    }
    ++outCount;
  };

  u64 ra[32], rb[32];
  auto loadc = [&](u64* dst, int c) {
    const u64* p = base + ((size_t)c * 64 + h * 32) * NW_ + w;
#pragma unroll
    for (int k = 0; k < 32; ++k) dst[k] = p[(size_t)k * NW_];
  };
  auto chunk = [&](u64* cur, int c) -> bool {        // returns done
    u64 rm = __shfl(removed, c);
    unsigned rml = (unsigned)rm, rmh = (unsigned)(rm >> 32);
#pragma unroll
    for (int k = 0; k < 32; ++k) {
      unsigned dlo = __builtin_amdgcn_readlane((unsigned)cur[k], c);
      unsigned dhi = __builtin_amdgcn_readlane((unsigned)(cur[k] >> 32), c);
      if (!((rml >> k) & 1u)) { rml |= dlo; rmh |= dhi; }
    }
#pragma unroll
    for (int k = 0; k < 32; ++k) {
      unsigned dlo = __builtin_amdgcn_readlane((unsigned)cur[k], 32 + c);
      unsigned dhi = __builtin_amdgcn_readlane((unsigned)(cur[k] >> 32), 32 + c);
      if (!((rmh >> k) & 1u)) { rml |= dlo; rmh |= dhi; }
    }
    u64 rmfull = ((u64)rmh << 32) | rml;
    u64 kb = ~rmfull;
    while (kb) {
      if (outCount >= DET_) return true;
      int k = __builtin_ctzll(kb);
      kb &= kb - 1;
      emitRow(c * 64 + k, true);
    }
    if (outCount >= DET_) return true;
    unsigned kmask = h ? ~rmh : ~rml;
    u64 acc = 0;
#pragma unroll
    for (int k = 0; k < 32; ++k)
      acc |= ((kmask >> k) & 1u) ? cur[k] : 0ull;
    acc |= __shfl_xor(acc, 32);
    removed = (l == c) ? rmfull : removed;
    if (l < 32 && l >= c) removed |= acc;
    return false;
  };

  bool done = false;
  loadc(ra, 0);
  for (int c = 0; c < NW_ && !done; c += 2) {
    if (c + 1 < NW_) loadc(rb, c + 1);
    done = chunk(ra, c);
    if (!done) {
      if (c + 2 < NW_) loadc(ra, c + 2);
      done = chunk(rb, c + 1);
    }
  }
  if (outCount < DET_) {
    for (int c2 = 0; c2 < NW_ && outCount < DET_; ++c2) {
      u64 rm = __shfl(removed, c2);
      while (rm && outCount < DET_) {
        int k = __builtin_ctzll(rm);
        rm &= rm - 1;
        emitRow(c2 * 64 + k, false);
      }
    }
  }
}

extern "C" void kernel_launch(void* const* d_in, const int* in_sizes, int n_in,
                              void* d_out, int out_size, void* d_ws, size_t ws_size,
                              hipStream_t stream) {
  const float* label_pre = (const float*)d_in[0];
  const float* bbox_pre = (const float*)d_in[1];
  const float* props = (const float*)d_in[2];
  float* out = (float*)d_out;

  char* ws = (char*)d_ws;
  size_t off = 0;
  auto alloc = [&](size_t bytes) -> void* {
    void* p = ws + off;
    off = (off + bytes + 255) & ~(size_t)255;
    return p;
  };

  uint32_t* keys = (uint32_t*)alloc((size_t)B_ * NC_ * 4);
  // ---- memset region: fineHist only (~221 KB) ----
  size_t zero_begin = off;
  uint32_t* fineHist = (uint32_t*)alloc((size_t)B_ * NBIN_ * 4);
  size_t zero_end = off;
  // ---- zeroed by k_scores (cnt+cand contiguous) ----
  uint32_t* cnt = (uint32_t*)alloc((size_t)B_ * SLOTS_ * 16 * 4);   // 16384 B
  u64* cand = (u64*)alloc((size_t)B_ * CAND_ * 8);                  // 262144 B
  // ---- zeroed by k_compact (top arrays contiguous) ----
  float* topScore = (float*)alloc((size_t)B_ * KP_ * 4);            // 65536 B
  int* topLabel = (int*)alloc((size_t)B_ * KP_ * 4);                // 65536 B
  float* topBox = (float*)alloc((size_t)B_ * KP_ * 16);             // 524288 B
  float* nmsBox = (float*)alloc((size_t)B_ * KP_ * 16);             // 524288 B
  // ---- no zeroing needed ----
  u64* sup = (u64*)alloc((size_t)B_ * KP_ * NW_ * 8);
  uint32_t* rankPart = (uint32_t*)alloc((size_t)B_ * RJS_ * CAND_ * 4);

  if (off > ws_size) return;  // workspace too small -> fail visibly

  uint4* zcc = (uint4*)cnt;
  int zccN = (int)(((size_t)B_ * SLOTS_ * 16 * 4 + (size_t)B_ * CAND_ * 8) / 16);   // 17408
  uint4* ztop = (uint4*)topScore;
  int ztopN = (int)(((size_t)B_ * KP_ * 4 * 2 + (size_t)B_ * KP_ * 16 * 2) / 16);   // 73728

  hipMemsetAsync(ws + zero_begin, 0, zero_end - zero_begin, stream);

  k_scores<<<B_ * IB_, 256, 0, stream>>>(label_pre, keys, fineHist, zcc, zccN);
  k_compact<<<B_ * NBLK_, 256, 0, stream>>>(keys, fineHist, cnt, cand, ztop, ztopN);
  k_rank<<<B_ * RIB_ * RJS_, RT_, 0, stream>>>(cand, rankPart);
  k_scatter<<<B_ * IBK_, 256, 0, stream>>>(cand, rankPart, bbox_pre, props,
                                           topScore, topLabel, topBox, nmsBox);
  k_supmat<<<B_ * 528, 64, 0, stream>>>(nmsBox, sup);
  k_nms_scan<<<B_, 64, 0, stream>>>(sup, topScore, topLabel, topBox, out);
}

// Round 7
// 193.655 us; speedup vs baseline: 2.8801x; 1.2321x over previous
//
#include <hip/hip_runtime.h>
#include <stdint.h>

#define B_ 8
#define N_ 4000
#define C_ 80
#define NC_ (N_ * C_)          // 320000 candidates per image
#define KP_ 2048               // K_PRE
#define CAND_ 4096             // compaction capacity = SLOTS_*SLOTCAP_
#define SLOTS_ 32
#define SLOTCAP_ 128
#define DET_ 100
#define NW_ 32                 // u64 words per NMS row (2048 bits)
#define CLIP_ 4.135166556742356f

#define PB_ 16                 // proposals per k_scores block (proven shape)
#define IB_ (N_ / PB_)         // 250 blocks per image
#define CB_ 64                 // coarse bins ((key>>20)-960)
#define FB_ 128                // fine bins ((key>>13)&127)
#define SEGB_ 64               // refine/compact blocks per image
#define U4PT_ 5                // uint4 per thread in refine/compact (64*256*5 >= 80000)

#define RT_ 256                // threads per rank block
#define RI_ 4                  // i-keys per thread (amortize LDS broadcast 4x)
#define RJS_ 16                // j-slices
#define RSL_ (CAND_ / RJS_)    // 256 keys per slice
#define RIB_ (CAND_ / (RT_ * RI_))  // 4 i-blocks per image
#define IBK_ (CAND_ / 256)     // 16 scatter blocks per image

typedef unsigned long long u64;

__device__ __forceinline__ void decode4(const float4 pr, const float4 d,
                                        float& x1, float& y1, float& x2, float& y2) {
  float w = pr.z - pr.x, h = pr.w - pr.y;
  float cx = pr.x + 0.5f * w, cy = pr.y + 0.5f * h;
  float dx = d.x / 10.0f, dy = d.y / 10.0f;
  float dw = fminf(d.z / 5.0f, CLIP_), dh = fminf(d.w / 5.0f, CLIP_);
  float pcx = dx * w + cx, pcy = dy * h + cy;
  float pw = expf(dw) * w, ph = expf(dh) * h;
  x1 = pcx - 0.5f * pw; y1 = pcy - 0.5f * ph;
  x2 = pcx + 0.5f * pw; y2 = pcy + 0.5f * ph;
}

// Shared helper: sum the 250 per-block coarse partials for image b into
// a 64-entry coarse histogram (4-wave split, L2-hot), leave value for lane t<64.
__device__ __forceinline__ uint32_t coarse_sum(const uint32_t* __restrict__ histPart,
                                               int b, int t, uint32_t (*wsum)[CB_]) {
  int l = t & 63, wv = t >> 6;
  uint32_t v = 0;
  for (int j = wv; j < IB_; j += 4)
    v += histPart[((size_t)b * IB_ + j) * CB_ + l];
  wsum[wv][l] = v;
  __syncthreads();
  return (t < CB_) ? (wsum[0][t] + wsum[1][t] + wsum[2][t] + wsum[3][t]) : 0u;
}

// K1: FUSED softmax + keys + LDS coarse histogram -> PLAIN-STORE partials.
// ROUND-6 LESSON: no contended global atomics (the 6912-bin global hist cost
// 65us in atomic serialization + write amplification). Also zero-stores the
// {fineHist,cnt,cand,top arrays} region -> memset dispatch eliminated.
__global__ __launch_bounds__(256) void k_scores(const float* __restrict__ logits,
                                                uint32_t* __restrict__ keys,
                                                uint32_t* __restrict__ histPart,
                                                uint4* __restrict__ zr, int zrN) {
  __shared__ float lds[PB_ * 81];
  __shared__ float mArr[PB_], dArr[PB_];
  __shared__ uint32_t hcnt[CB_];
  int blk = blockIdx.x;                 // 0 .. B_*IB_-1
  int b = blk / IB_, lb = blk - b * IB_;
  int p0 = b * N_ + lb * PB_;           // global proposal base
  int t = threadIdx.x;
  for (int i = blk * 256 + t; i < zrN; i += B_ * IB_ * 256)
    zr[i] = make_uint4(0u, 0u, 0u, 0u);
  if (t < CB_) hcnt[t] = 0;
  const float4* src = (const float4*)(logits + (size_t)p0 * 81);
  for (int k = t; k < PB_ * 81 / 4; k += 256) ((float4*)lds)[k] = src[k];
  __syncthreads();
  if (t < PB_) {
    const float* lp = lds + t * 81;
    float m = lp[0];
    for (int i = 1; i <= C_; ++i) m = fmaxf(m, lp[i]);
    float denom = 0.f;
    for (int i = 0; i <= C_; ++i) denom += expf(lp[i] - m);
    mArr[t] = m; dArr[t] = denom;
  }
  __syncthreads();
#pragma unroll
  for (int iter = 0; iter < PB_ * C_ / 256; ++iter) {   // 5 iters
    int e = iter * 256 + t;             // 0..1279
    int pp = e / C_, c = e - pp * C_;
    float lv = lds[pp * 81 + c + 1];
    float score = expf(lv - mArr[pp]) / dArr[pp];
    uint32_t key = 0;
    if (score > 0.01f) {
      key = __float_as_uint(score);
      atomicAdd(&hcnt[(key >> 20) - 960], 1u);          // LDS atomic only
    }
    keys[(size_t)p0 * C_ + e] = key;                    // coalesced
  }
  __syncthreads();
  if (t < CB_) histPart[((size_t)b * IB_ + lb) * CB_ + t] = hcnt[t];  // plain store
}

// K2: coarse selection (from summed partials) + fine histogram in LDS,
// flushed once per block (128 cheap global atomics). 64 blocks/image.
__global__ __launch_bounds__(256) void k_refine(const uint32_t* __restrict__ keys,
                                                const uint32_t* __restrict__ histPart,
                                                uint32_t* __restrict__ fineHist) {
  __shared__ uint32_t wsum[4][CB_];
  __shared__ int s_cb;
  __shared__ uint32_t hf[FB_];
  int blk = blockIdx.x;
  int b = blk / SEGB_, lb = blk - b * SEGB_;
  int t = threadIdx.x;
  if (t < FB_) hf[t] = 0;
  uint32_t cv = coarse_sum(histPart, b, t, wsum);
  if (t < CB_) {
    uint32_t v = cv;
#pragma unroll
    for (int d = 1; d < 64; d <<= 1) {
      uint32_t o = __shfl_down(v, d);
      v += (t + d < 64) ? o : 0;
    }
    uint32_t nxt = __shfl_down(v, 1);
    if (t == 63) nxt = 0;
    uint32_t total = __shfl(v, 0);
    if (t == 0 && total < KP_) s_cb = -1;
    if (total >= KP_ && v >= KP_ && nxt < KP_) s_cb = t;
  }
  __syncthreads();
  int cb = s_cb;
  if (cb < 0) return;                   // fineHist stays zeroed; compact handles
  uint32_t want = (uint32_t)(cb + 960);
  const uint4* kp4 = (const uint4*)(keys + (size_t)b * NC_);
#pragma unroll
  for (int q = 0; q < U4PT_; ++q) {
    int ti = lb * (256 * U4PT_) + q * 256 + t;
    if (ti < NC_ / 4) {
      uint4 k4 = kp4[ti];
      uint32_t kv[4] = {k4.x, k4.y, k4.z, k4.w};
#pragma unroll
      for (int qq = 0; qq < 4; ++qq)
        if ((kv[qq] >> 20) == want)
          atomicAdd(&hf[(kv[qq] >> 13) & (FB_ - 1)], 1u);   // LDS atomic
    }
  }
  __syncthreads();
  if (t < FB_ && hf[t]) atomicAdd(&fineHist[b * FB_ + t], hf[t]);  // 128/block
}

// K3: threshold (coarse scan from partials + fine scan, math verbatim from
// the validated round-3 kernel) + compaction. 64 blocks/image; slot mapping
// stays the identical function of ti.
__global__ __launch_bounds__(256) void k_compact(const uint32_t* __restrict__ keys,
                                                 const uint32_t* __restrict__ histPart,
                                                 const uint32_t* __restrict__ fineHist,
                                                 uint32_t* __restrict__ cnt,
                                                 u64* __restrict__ cand) {
  __shared__ uint32_t wsum[4][CB_];
  __shared__ int s_cb;
  __shared__ uint32_t s_tail;
  __shared__ uint32_t s_thr;
  int blk = blockIdx.x;
  int b = blk / SEGB_, lb = blk - b * SEGB_;
  int t = threadIdx.x;
  uint32_t cv = coarse_sum(histPart, b, t, wsum);
  if (t < CB_) {
    uint32_t v = cv;
#pragma unroll
    for (int d = 1; d < 64; d <<= 1) {
      uint32_t o = __shfl_down(v, d);
      v += (t + d < 64) ? o : 0;
    }
    uint32_t nxt = __shfl_down(v, 1);
    if (t == 63) nxt = 0;
    uint32_t total = __shfl(v, 0);
    if (t == 0 && total < KP_) { s_cb = -1; s_tail = 0; }
    if (total >= KP_ && v >= KP_ && nxt < KP_) { s_cb = t; s_tail = nxt; }
  }
  __syncthreads();
  int cb = s_cb;
  if (cb < 0) {
    if (t == 0) s_thr = 1u;                 // pass all nonzero keys
  } else if (t < 64) {
    uint32_t f0 = fineHist[b * FB_ + 2 * t];
    uint32_t f1 = fineHist[b * FB_ + 2 * t + 1];
    uint32_t v = f0 + f1;
#pragma unroll
    for (int d = 1; d < 64; d <<= 1) {
      uint32_t o = __shfl_down(v, d);
      v += (t + d < 64) ? o : 0;
    }
    uint32_t nxt = __shfl_down(v, 1);
    if (t == 63) nxt = 0;
    uint32_t tail = s_tail;
    bool c0 = (tail + v >= KP_);
    bool c1 = (tail + nxt + f1 >= KP_);
    bool cN = (tail + nxt >= KP_);
    if (c0 && !c1) s_thr = ((uint32_t)(cb + 960) << 20) | ((uint32_t)(2 * t) << 13);
    if (c1 && !cN) s_thr = ((uint32_t)(cb + 960) << 20) | ((uint32_t)(2 * t + 1) << 13);
  }
  __syncthreads();
  uint32_t thrb = s_thr;
  const uint4* kp4 = (const uint4*)(keys + (size_t)b * NC_);
#pragma unroll
  for (int q = 0; q < U4PT_; ++q) {
    int ti = lb * (256 * U4PT_) + q * 256 + t;
    if (ti >= NC_ / 4) break;
    uint4 k4 = kp4[ti];
    int slot = (ti >> 4) & (SLOTS_ - 1);
    uint32_t kv[4] = {k4.x, k4.y, k4.z, k4.w};
    int ns = 0;
#pragma unroll
    for (int qq = 0; qq < 4; ++qq) ns += (kv[qq] >= thrb) ? 1 : 0;
    if (ns == 0) continue;
    uint32_t pos = atomicAdd(&cnt[(b * SLOTS_ + slot) * 16], (uint32_t)ns);
    u64* seg = cand + (size_t)b * CAND_ + slot * SLOTCAP_;
    uint32_t baseIdx = (uint32_t)(ti * 4);
#pragma unroll
    for (int qq = 0; qq < 4; ++qq) {
      if (kv[qq] >= thrb) {
        if (pos < SLOTCAP_)
          seg[pos] = ((u64)kv[qq] << 32) | (uint32_t)(~(baseIdx + qq));
        ++pos;
      }
    }
  }
}

// K4: i-blocked j-split rank — plain partial writes only (no fences).
__global__ __launch_bounds__(256) void k_rank(const u64* __restrict__ cand,
                                              uint32_t* __restrict__ rankPart) {
  __shared__ u64 sh[RSL_];
  int blk = blockIdx.x;                  // b * (RIB_*RJS_) + lb * RJS_ + js
  int b = blk / (RIB_ * RJS_);
  int rem = blk - b * (RIB_ * RJS_);
  int lb = rem / RJS_, js = rem - lb * RJS_;
  int t = threadIdx.x;
  const u64* cb2 = cand + (size_t)b * CAND_;
  if (t < RSL_ / 2)
    ((ulonglong2*)sh)[t] = ((const ulonglong2*)(cb2 + js * RSL_))[t];
  int base = lb * (RT_ * RI_) + t;
  u64 ki[RI_];
#pragma unroll
  for (int q = 0; q < RI_; ++q) ki[q] = cb2[base + q * RT_];   // coalesced
  __syncthreads();
  int cnt4[RI_] = {0, 0, 0, 0};
#pragma unroll 4
  for (int j2 = 0; j2 < RSL_ / 2; ++j2) {  // 128 uniform ds_read_b128
    ulonglong2 v = ((const ulonglong2*)sh)[j2];
#pragma unroll
    for (int q = 0; q < RI_; ++q) {
      cnt4[q] += (v.x > ki[q]) ? 1 : 0;
      cnt4[q] += (v.y > ki[q]) ? 1 : 0;
    }
  }
  uint32_t* rp = rankPart + ((size_t)(b * RJS_ + js)) * CAND_ + base;
#pragma unroll
  for (int q = 0; q < RI_; ++q) rp[q * RT_] = (uint32_t)cnt4[q];  // coalesced
}

// K5: sum the RJS_ partial ranks (L2-hot) and scatter: decode + write top
// arrays at position rank. Sentinel slots keep the zero-init.
__global__ __launch_bounds__(256) void k_scatter(
    const u64* __restrict__ cand, const uint32_t* __restrict__ rankPart,
    const float* __restrict__ bbox, const float* __restrict__ props,
    float* __restrict__ topScore, int* __restrict__ topLabel,
    float* __restrict__ topBox, float* __restrict__ nmsBox) {
  int blk = blockIdx.x;                  // B_ * IBK_
  int b = blk / IBK_, lb = blk - b * IBK_;
  int t = threadIdx.x;
  int i = lb * 256 + t;
  u64 ki = cand[(size_t)b * CAND_ + i];
  if (ki == 0ull) return;
  uint32_t r = 0;
#pragma unroll
  for (int js = 0; js < RJS_; ++js)
    r += rankPart[((size_t)(b * RJS_ + js)) * CAND_ + i];
  if (r >= KP_) return;
  uint32_t sbits = (uint32_t)(ki >> 32);
  uint32_t idx = ~((uint32_t)ki);
  int n = idx / C_, c = idx % C_;
  float4 pr4 = ((const float4*)props)[(size_t)b * N_ + n];
  float4 d = ((const float4*)(bbox + ((size_t)b * N_ + n) * ((C_ + 1) * 4)))[c + 1];
  float x1, y1, x2, y2;
  decode4(pr4, d, x1, y1, x2, y2);
  float off = (float)(c + 1) * 4096.0f;
  size_t o = (size_t)b * KP_ + (size_t)r;
  topScore[o] = __uint_as_float(sbits);
  topLabel[o] = c + 1;
  ((float4*)topBox)[o] = make_float4(x1, y1, x2, y2);
  ((float4*)nmsBox)[o] = make_float4(x1 + off, y1 + off, x2 + off, y2 + off);
}

// K6: suppression bitmatrix — triangular grid (528 tiles/image).
__global__ __launch_bounds__(64) void k_supmat(const float* __restrict__ nmsBox,
                                               u64* __restrict__ sup) {
  int blk = blockIdx.x;
  int b = blk / 528, r = blk - b * 528;
  int ti = 0, rem = r;
  while (rem >= 32 - ti) { rem -= 32 - ti; ++ti; }
  int tj = ti + rem;
  __shared__ float4 shj[64];
  __shared__ float sha[64];
  int l = threadIdx.x;
  const float4* boxes = (const float4*)(nmsBox + (size_t)b * KP_ * 4);
  float4 bj0 = boxes[tj * 64 + l];
  shj[l] = bj0;
  sha[l] = fmaxf(bj0.z - bj0.x, 0.f) * fmaxf(bj0.w - bj0.y, 0.f);
  int i = ti * 64 + l;
  float4 bi = boxes[i];
  float areai = fmaxf(bi.z - bi.x, 0.f) * fmaxf(bi.w - bi.y, 0.f);
  __syncthreads();
  u64 bits = 0;
  for (int jj = 0; jj < 64; ++jj) {
    int j = tj * 64 + jj;
    if (j > i) {
      float4 bj = shj[jj];
      float ltx = fmaxf(bi.x, bj.x), lty = fmaxf(bi.y, bj.y);
      float rbx = fminf(bi.z, bj.z), rby = fminf(bi.w, bj.w);
      float iw = fmaxf(rbx - ltx, 0.f), ih = fmaxf(rby - lty, 0.f);
      float inter = iw * ih;
      float uni = areai + sha[jj] - inter;
      float iou = inter / fmaxf(uni, 1e-9f);
      if (iou > 0.5f) bits |= (1ull << jj);
    }
  }
  sup[((size_t)b * KP_ + i) * NW_ + tj] = bits;
}

// K7: chunked greedy NMS with early exit + direct output emission.
__global__ __launch_bounds__(64) void k_nms_scan(const u64* __restrict__ sup,
                                                 const float* __restrict__ topScore,
                                                 const int* __restrict__ topLabel,
                                                 const float* __restrict__ topBox,
                                                 float* __restrict__ out) {
  int b = blockIdx.x, l = threadIdx.x;
  int h = l >> 5, w = l & 31;
  const u64* base = sup + (size_t)b * KP_ * NW_;
  const float* ts = topScore + (size_t)b * KP_;
  const int* tl = topLabel + (size_t)b * KP_;
  const float4* tb = (const float4*)(topBox + (size_t)b * KP_ * 4);
  unsigned m32 = 0;
#pragma unroll
  for (int j = 0; j < 8; ++j) {
    float4 s4 = ((const float4*)ts)[l * 8 + j];
    if (!(s4.x > 0.f)) m32 |= 1u << (4 * j + 0);
    if (!(s4.y > 0.f)) m32 |= 1u << (4 * j + 1);
    if (!(s4.z > 0.f)) m32 |= 1u << (4 * j + 2);
    if (!(s4.w > 0.f)) m32 |= 1u << (4 * j + 3);
  }
  u64 removed = ((u64)__shfl(m32, 2 * w + 1) << 32) | (u64)__shfl(m32, 2 * w);

  int outCount = 0;                                  // wave-uniform
  auto emitRow = [&](int row, bool kept) {
    if (l == (outCount & 63)) {
      float4 bx = tb[row];
      out[((size_t)b * DET_ + outCount) * 4 + 0] = bx.x;
      out[((size_t)b * DET_ + outCount) * 4 + 1] = bx.y;
      out[((size_t)b * DET_ + outCount) * 4 + 2] = bx.z;
      out[((size_t)b * DET_ + outCount) * 4 + 3] = bx.w;
      out[B_ * DET_ * 4 + (size_t)b * DET_ + outCount] = kept ? ts[row] : -1.0f;
      out[B_ * DET_ * 4 + B_ * DET_ + (size_t)b * DET_ + outCount] = (float)tl[row];
    }
    ++outCount;
  };

  u64 ra[32], rb[32];
  auto loadc = [&](u64* dst, int c) {
    const u64* p = base + ((size_t)c * 64 + h * 32) * NW_ + w;
#pragma unroll
    for (int k = 0; k < 32; ++k) dst[k] = p[(size_t)k * NW_];
  };
  auto chunk = [&](u64* cur, int c) -> bool {        // returns done
    u64 rm = __shfl(removed, c);
    unsigned rml = (unsigned)rm, rmh = (unsigned)(rm >> 32);
#pragma unroll
    for (int k = 0; k < 32; ++k) {
      unsigned dlo = __builtin_amdgcn_readlane((unsigned)cur[k], c);
      unsigned dhi = __builtin_amdgcn_readlane((unsigned)(cur[k] >> 32), c);
      if (!((rml >> k) & 1u)) { rml |= dlo; rmh |= dhi; }
    }
#pragma unroll
    for (int k = 0; k < 32; ++k) {
      unsigned dlo = __builtin_amdgcn_readlane((unsigned)cur[k], 32 + c);
      unsigned dhi = __builtin_amdgcn_readlane((unsigned)(cur[k] >> 32), 32 + c);
      if (!((rmh >> k) & 1u)) { rml |= dlo; rmh |= dhi; }
    }
    u64 rmfull = ((u64)rmh << 32) | rml;
    u64 kb = ~rmfull;
    while (kb) {
      if (outCount >= DET_) return true;
      int k = __builtin_ctzll(kb);
      kb &= kb - 1;
      emitRow(c * 64 + k, true);
    }
    if (outCount >= DET_) return true;
    unsigned kmask = h ? ~rmh : ~rml;
    u64 acc = 0;
#pragma unroll
    for (int k = 0; k < 32; ++k)
      acc |= ((kmask >> k) & 1u) ? cur[k] : 0ull;
    acc |= __shfl_xor(acc, 32);
    removed = (l == c) ? rmfull : removed;
    if (l < 32 && l >= c) removed |= acc;
    return false;
  };

  bool done = false;
  loadc(ra, 0);
  for (int c = 0; c < NW_ && !done; c += 2) {
    if (c + 1 < NW_) loadc(rb, c + 1);
    done = chunk(ra, c);
    if (!done) {
      if (c + 2 < NW_) loadc(ra, c + 2);
      done = chunk(rb, c + 1);
    }
  }
  if (outCount < DET_) {
    for (int c2 = 0; c2 < NW_ && outCount < DET_; ++c2) {
      u64 rm = __shfl(removed, c2);
      while (rm && outCount < DET_) {
        int k = __builtin_ctzll(rm);
        rm &= rm - 1;
        emitRow(c2 * 64 + k, false);
      }
    }
  }
}

extern "C" void kernel_launch(void* const* d_in, const int* in_sizes, int n_in,
                              void* d_out, int out_size, void* d_ws, size_t ws_size,
                              hipStream_t stream) {
  const float* label_pre = (const float*)d_in[0];
  const float* bbox_pre = (const float*)d_in[1];
  const float* props = (const float*)d_in[2];
  float* out = (float*)d_out;

  char* ws = (char*)d_ws;
  size_t off = 0;
  auto alloc = [&](size_t bytes) -> void* {
    void* p = ws + off;
    off = (off + bytes + 255) & ~(size_t)255;
    return p;
  };

  uint32_t* keys = (uint32_t*)alloc((size_t)B_ * NC_ * 4);
  uint32_t* histPart = (uint32_t*)alloc((size_t)B_ * IB_ * CB_ * 4);  // written unconditionally
  // ---- single zero region, zero-stored by k_scores (all 256B multiples,
  //      so alloc() padding keeps it contiguous) ----
  size_t zero_begin = off;
  uint32_t* fineHist = (uint32_t*)alloc((size_t)B_ * FB_ * 4);        // 4096 B
  uint32_t* cnt = (uint32_t*)alloc((size_t)B_ * SLOTS_ * 16 * 4);     // 16384 B
  u64* cand = (u64*)alloc((size_t)B_ * CAND_ * 8);                    // 262144 B
  float* topScore = (float*)alloc((size_t)B_ * KP_ * 4);              // 65536 B
  int* topLabel = (int*)alloc((size_t)B_ * KP_ * 4);                  // 65536 B
  float* topBox = (float*)alloc((size_t)B_ * KP_ * 16);               // 524288 B
  float* nmsBox = (float*)alloc((size_t)B_ * KP_ * 16);               // 524288 B
  size_t zero_end = off;
  // ---- no zeroing needed ----
  u64* sup = (u64*)alloc((size_t)B_ * KP_ * NW_ * 8);
  uint32_t* rankPart = (uint32_t*)alloc((size_t)B_ * RJS_ * CAND_ * 4);

  if (off > ws_size) return;  // workspace too small -> fail visibly

  uint4* zr = (uint4*)(ws + zero_begin);
  int zrN = (int)((zero_end - zero_begin) / 16);

  k_scores<<<B_ * IB_, 256, 0, stream>>>(label_pre, keys, histPart, zr, zrN);
  k_refine<<<B_ * SEGB_, 256, 0, stream>>>(keys, histPart, fineHist);
  k_compact<<<B_ * SEGB_, 256, 0, stream>>>(keys, histPart, fineHist, cnt, cand);
  k_rank<<<B_ * RIB_ * RJS_, RT_, 0, stream>>>(cand, rankPart);
  k_scatter<<<B_ * IBK_, 256, 0, stream>>>(cand, rankPart, bbox_pre, props,
                                           topScore, topLabel, topBox, nmsBox);
  k_supmat<<<B_ * 528, 64, 0, stream>>>(nmsBox, sup);
  k_nms_scan<<<B_, 64, 0, stream>>>(sup, topScore, topLabel, topBox, out);
}

// Round 9
// 186.235 us; speedup vs baseline: 2.9948x; 1.0398x over previous
//
#include <hip/hip_runtime.h>
#include <stdint.h>

#define B_ 8
#define N_ 4000
#define C_ 80
#define NC_ (N_ * C_)          // 320000 candidates per image
#define KP_ 2048               // K_PRE
#define CAND_ 4096             // compaction capacity = SLOTS_*SLOTCAP_
#define SLOTS_ 32
#define SLOTCAP_ 128
#define DET_ 100
#define NW_ 32                 // u64 words per NMS row (2048 bits)
#define CLIP_ 4.135166556742356f

#define PB_ 16                 // proposals per k_scores block (proven shape)
#define IB_ (N_ / PB_)         // 250 blocks per image
#define CB_ 64                 // coarse bins ((key>>20)-960)
#define SEGB_ 64               // compact blocks per image
#define U4PT_ 5                // uint4 per thread in compact (64*256*5 >= 80000)

#define RT_ 256                // threads per rank block
#define RI_ 4                  // i-keys per thread (amortize LDS broadcast 4x)
#define RJS_ 16                // j-slices
#define RSL_ (CAND_ / RJS_)    // 256 keys per slice
#define RIB_ (CAND_ / (RT_ * RI_))  // 4 i-blocks per image
#define IBK_ (CAND_ / 256)     // 16 scatter blocks per image

typedef unsigned long long u64;

__device__ __forceinline__ void decode4(const float4 pr, const float4 d,
                                        float& x1, float& y1, float& x2, float& y2) {
  float w = pr.z - pr.x, h = pr.w - pr.y;
  float cx = pr.x + 0.5f * w, cy = pr.y + 0.5f * h;
  float dx = d.x / 10.0f, dy = d.y / 10.0f;
  float dw = fminf(d.z / 5.0f, CLIP_), dh = fminf(d.w / 5.0f, CLIP_);
  float pcx = dx * w + cx, pcy = dy * h + cy;
  float pw = expf(dw) * w, ph = expf(dh) * h;
  x1 = pcx - 0.5f * pw; y1 = pcy - 0.5f * ph;
  x2 = pcx + 0.5f * pw; y2 = pcy + 0.5f * ph;
}

// Sum the 250 per-block coarse partials for image b (coalesced 256B rows,
// L2-hot); returns this lane's coarse-bin total for t<64.
__device__ __forceinline__ uint32_t coarse_sum(const uint32_t* __restrict__ histPart,
                                               int b, int t, uint32_t (*wsum)[CB_]) {
  int l = t & 63, wv = t >> 6;
  uint32_t v = 0;
  for (int j = wv; j < IB_; j += 4)
    v += histPart[((size_t)b * IB_ + j) * CB_ + l];
  wsum[wv][l] = v;
  __syncthreads();
  return (t < CB_) ? (wsum[0][t] + wsum[1][t] + wsum[2][t] + wsum[3][t]) : 0u;
}

// K1: FUSED softmax + keys + LDS coarse histogram -> PLAIN-STORE partials.
// (No contended global atomics — round-6 lesson; no device fences — round-5
// lesson.) Also zero-stores {cnt,cand,top arrays} -> no memset dispatch.
__global__ __launch_bounds__(256) void k_scores(const float* __restrict__ logits,
                                                uint32_t* __restrict__ keys,
                                                uint32_t* __restrict__ histPart,
                                                uint4* __restrict__ zr, int zrN) {
  __shared__ float lds[PB_ * 81];
  __shared__ float mArr[PB_], dArr[PB_];
  __shared__ uint32_t hcnt[CB_];
  int blk = blockIdx.x;                 // 0 .. B_*IB_-1
  int b = blk / IB_, lb = blk - b * IB_;
  int p0 = b * N_ + lb * PB_;           // global proposal base
  int t = threadIdx.x;
  for (int i = blk * 256 + t; i < zrN; i += B_ * IB_ * 256)
    zr[i] = make_uint4(0u, 0u, 0u, 0u);
  if (t < CB_) hcnt[t] = 0;
  const float4* src = (const float4*)(logits + (size_t)p0 * 81);
  for (int k = t; k < PB_ * 81 / 4; k += 256) ((float4*)lds)[k] = src[k];
  __syncthreads();
  if (t < PB_) {
    const float* lp = lds + t * 81;
    float m = lp[0];
    for (int i = 1; i <= C_; ++i) m = fmaxf(m, lp[i]);
    float denom = 0.f;
    for (int i = 0; i <= C_; ++i) denom += expf(lp[i] - m);
    mArr[t] = m; dArr[t] = denom;
  }
  __syncthreads();
#pragma unroll
  for (int iter = 0; iter < PB_ * C_ / 256; ++iter) {   // 5 iters
    int e = iter * 256 + t;             // 0..1279
    int pp = e / C_, c = e - pp * C_;
    float lv = lds[pp * 81 + c + 1];
    float score = expf(lv - mArr[pp]) / dArr[pp];
    uint32_t key = 0;
    if (score > 0.01f) {
      key = __float_as_uint(score);
      atomicAdd(&hcnt[(key >> 20) - 960], 1u);          // LDS atomic only
    }
    keys[(size_t)p0 * C_ + e] = key;                    // coalesced
  }
  __syncthreads();
  if (t < CB_) histPart[((size_t)b * IB_ + lb) * CB_ + t] = hcnt[t];  // plain store
}

// K2: COARSE-ONLY threshold + compaction (k_refine + fineHist ELIMINATED).
// thr = start of the coarse bin where the top-down cumulative crosses KP_.
// All top-KP_ keys are >= thr, so they all survive; the exact rank stage
// (K3/K4) then reproduces the reference top-2048 exactly. Capacity check:
// survivors = KP_ + sub-bin tail (~500 expected) << CAND_=4096; per-slot
// load ~81 avg << SLOTCAP_=128. Harness validation is the backstop.
__global__ __launch_bounds__(256) void k_compact(const uint32_t* __restrict__ keys,
                                                 const uint32_t* __restrict__ histPart,
                                                 uint32_t* __restrict__ cnt,
                                                 u64* __restrict__ cand) {
  __shared__ uint32_t wsum[4][CB_];
  __shared__ uint32_t s_thr;
  int blk = blockIdx.x;
  int b = blk / SEGB_, lb = blk - b * SEGB_;
  int t = threadIdx.x;
  uint32_t cv = coarse_sum(histPart, b, t, wsum);
  if (t < CB_) {
    uint32_t v = cv;
#pragma unroll
    for (int d = 1; d < 64; d <<= 1) {                  // wave suffix scan
      uint32_t o = __shfl_down(v, d);
      v += (t + d < 64) ? o : 0;
    }
    uint32_t nxt = __shfl_down(v, 1);
    if (t == 63) nxt = 0;
    uint32_t total = __shfl(v, 0);
    if (t == 0 && total < KP_) s_thr = 1u;              // pass all nonzero keys
    if (total >= KP_ && v >= KP_ && nxt < KP_)
      s_thr = ((uint32_t)(t + 960)) << 20;              // coarse-bin floor
  }
  __syncthreads();
  uint32_t thrb = s_thr;
  const uint4* kp4 = (const uint4*)(keys + (size_t)b * NC_);
#pragma unroll
  for (int q = 0; q < U4PT_; ++q) {
    int ti = lb * (256 * U4PT_) + q * 256 + t;
    if (ti >= NC_ / 4) break;
    uint4 k4 = kp4[ti];
    int slot = (ti >> 4) & (SLOTS_ - 1);
    uint32_t kv[4] = {k4.x, k4.y, k4.z, k4.w};
    int ns = 0;
#pragma unroll
    for (int qq = 0; qq < 4; ++qq) ns += (kv[qq] >= thrb) ? 1 : 0;
    if (ns == 0) continue;
    uint32_t pos = atomicAdd(&cnt[(b * SLOTS_ + slot) * 16], (uint32_t)ns);
    u64* seg = cand + (size_t)b * CAND_ + slot * SLOTCAP_;
    uint32_t baseIdx = (uint32_t)(ti * 4);
#pragma unroll
    for (int qq = 0; qq < 4; ++qq) {
      if (kv[qq] >= thrb) {
        if (pos < SLOTCAP_)
          seg[pos] = ((u64)kv[qq] << 32) | (uint32_t)(~(baseIdx + qq));
        ++pos;
      }
    }
  }
}

// K3: i-blocked j-split rank — plain partial writes only (no fences).
__global__ __launch_bounds__(256) void k_rank(const u64* __restrict__ cand,
                                              uint32_t* __restrict__ rankPart) {
  __shared__ u64 sh[RSL_];
  int blk = blockIdx.x;                  // b * (RIB_*RJS_) + lb * RJS_ + js
  int b = blk / (RIB_ * RJS_);
  int rem = blk - b * (RIB_ * RJS_);
  int lb = rem / RJS_, js = rem - lb * RJS_;
  int t = threadIdx.x;
  const u64* cb2 = cand + (size_t)b * CAND_;
  if (t < RSL_ / 2)
    ((ulonglong2*)sh)[t] = ((const ulonglong2*)(cb2 + js * RSL_))[t];
  int base = lb * (RT_ * RI_) + t;
  u64 ki[RI_];
#pragma unroll
  for (int q = 0; q < RI_; ++q) ki[q] = cb2[base + q * RT_];   // coalesced
  __syncthreads();
  int cnt4[RI_] = {0, 0, 0, 0};
#pragma unroll 4
  for (int j2 = 0; j2 < RSL_ / 2; ++j2) {  // 128 uniform ds_read_b128
    ulonglong2 v = ((const ulonglong2*)sh)[j2];
#pragma unroll
    for (int q = 0; q < RI_; ++q) {
      cnt4[q] += (v.x > ki[q]) ? 1 : 0;
      cnt4[q] += (v.y > ki[q]) ? 1 : 0;
    }
  }
  uint32_t* rp = rankPart + ((size_t)(b * RJS_ + js)) * CAND_ + base;
#pragma unroll
  for (int q = 0; q < RI_; ++q) rp[q * RT_] = (uint32_t)cnt4[q];  // coalesced
}

// K4: sum the RJS_ partial ranks (L2-hot) and scatter: decode + write top
// arrays at position rank. Sentinel slots keep the zero-init.
__global__ __launch_bounds__(256) void k_scatter(
    const u64* __restrict__ cand, const uint32_t* __restrict__ rankPart,
    const float* __restrict__ bbox, const float* __restrict__ props,
    float* __restrict__ topScore, int* __restrict__ topLabel,
    float* __restrict__ topBox, float* __restrict__ nmsBox) {
  int blk = blockIdx.x;                  // B_ * IBK_
  int b = blk / IBK_, lb = blk - b * IBK_;
  int t = threadIdx.x;
  int i = lb * 256 + t;
  u64 ki = cand[(size_t)b * CAND_ + i];
  if (ki == 0ull) return;
  uint32_t r = 0;
#pragma unroll
  for (int js = 0; js < RJS_; ++js)
    r += rankPart[((size_t)(b * RJS_ + js)) * CAND_ + i];
  if (r >= KP_) return;
  uint32_t sbits = (uint32_t)(ki >> 32);
  uint32_t idx = ~((uint32_t)ki);
  int n = idx / C_, c = idx % C_;
  float4 pr4 = ((const float4*)props)[(size_t)b * N_ + n];
  float4 d = ((const float4*)(bbox + ((size_t)b * N_ + n) * ((C_ + 1) * 4)))[c + 1];
  float x1, y1, x2, y2;
  decode4(pr4, d, x1, y1, x2, y2);
  float off = (float)(c + 1) * 4096.0f;
  size_t o = (size_t)b * KP_ + (size_t)r;
  topScore[o] = __uint_as_float(sbits);
  topLabel[o] = c + 1;
  ((float4*)topBox)[o] = make_float4(x1, y1, x2, y2);
  ((float4*)nmsBox)[o] = make_float4(x1 + off, y1 + off, x2 + off, y2 + off);
}

// K5: suppression bitmatrix — triangular grid (528 tiles/image).
__global__ __launch_bounds__(64) void k_supmat(const float* __restrict__ nmsBox,
                                               u64* __restrict__ sup) {
  int blk = blockIdx.x;
  int b = blk / 528, r = blk - b * 528;
  int ti = 0, rem = r;
  while (rem >= 32 - ti) { rem -= 32 - ti; ++ti; }
  int tj = ti + rem;
  __shared__ float4 shj[64];
  __shared__ float sha[64];
  int l = threadIdx.x;
  const float4* boxes = (const float4*)(nmsBox + (size_t)b * KP_ * 4);
  float4 bj0 = boxes[tj * 64 + l];
  shj[l] = bj0;
  sha[l] = fmaxf(bj0.z - bj0.x, 0.f) * fmaxf(bj0.w - bj0.y, 0.f);
  int i = ti * 64 + l;
  float4 bi = boxes[i];
  float areai = fmaxf(bi.z - bi.x, 0.f) * fmaxf(bi.w - bi.y, 0.f);
  __syncthreads();
  u64 bits = 0;
  for (int jj = 0; jj < 64; ++jj) {
    int j = tj * 64 + jj;
    if (j > i) {
      float4 bj = shj[jj];
      float ltx = fmaxf(bi.x, bj.x), lty = fmaxf(bi.y, bj.y);
      float rbx = fminf(bi.z, bj.z), rby = fminf(bi.w, bj.w);
      float iw = fmaxf(rbx - ltx, 0.f), ih = fmaxf(rby - lty, 0.f);
      float inter = iw * ih;
      float uni = areai + sha[jj] - inter;
      float iou = inter / fmaxf(uni, 1e-9f);
      if (iou > 0.5f) bits |= (1ull << jj);
    }
  }
  sup[((size_t)b * KP_ + i) * NW_ + tj] = bits;
}

// K6: chunked greedy NMS with early exit + direct output emission.
__global__ __launch_bounds__(64) void k_nms_scan(const u64* __restrict__ sup,
                                                 const float* __restrict__ topScore,
                                                 const int* __restrict__ topLabel,
                                                 const float* __restrict__ topBox,
                                                 float* __restrict__ out) {
  int b = blockIdx.x, l = threadIdx.x;
  int h = l >> 5, w = l & 31;
  const u64* base = sup + (size_t)b * KP_ * NW_;
  const float* ts = topScore + (size_t)b * KP_;
  const int* tl = topLabel + (size_t)b * KP_;
  const float4* tb = (const float4*)(topBox + (size_t)b * KP_ * 4);
  unsigned m32 = 0;
#pragma unroll
  for (int j = 0; j < 8; ++j) {
    float4 s4 = ((const float4*)ts)[l * 8 + j];
    if (!(s4.x > 0.f)) m32 |= 1u << (4 * j + 0);
    if (!(s4.y > 0.f)) m32 |= 1u << (4 * j + 1);
    if (!(s4.z > 0.f)) m32 |= 1u << (4 * j + 2);
    if (!(s4.w > 0.f)) m32 |= 1u << (4 * j + 3);
  }
  u64 removed = ((u64)__shfl(m32, 2 * w + 1) << 32) | (u64)__shfl(m32, 2 * w);

  int outCount = 0;                                  // wave-uniform
  auto emitRow = [&](int row, bool kept) {
    if (l == (outCount & 63)) {
      float4 bx = tb[row];
      out[((size_t)b * DET_ + outCount) * 4 + 0] = bx.x;
      out[((size_t)b * DET_ + outCount) * 4 + 1] = bx.y;
      out[((size_t)b * DET_ + outCount) * 4 + 2] = bx.z;
      out[((size_t)b * DET_ + outCount) * 4 + 3] = bx.w;
      out[B_ * DET_ * 4 + (size_t)b * DET_ + outCount] = kept ? ts[row] : -1.0f;
      out[B_ * DET_ * 4 + B_ * DET_ + (size_t)b * DET_ + outCount] = (float)tl[row];
    }
    ++outCount;
  };

  u64 ra[32], rb[32];
  auto loadc = [&](u64* dst, int c) {
    const u64* p = base + ((size_t)c * 64 + h * 32) * NW_ + w;
#pragma unroll
    for (int k = 0; k < 32; ++k) dst[k] = p[(size_t)k * NW_];
  };
  auto chunk = [&](u64* cur, int c) -> bool {        // returns done
    u64 rm = __shfl(removed, c);
    unsigned rml = (unsigned)rm, rmh = (unsigned)(rm >> 32);
#pragma unroll
    for (int k = 0; k < 32; ++k) {
      unsigned dlo = __builtin_amdgcn_readlane((unsigned)cur[k], c);
      unsigned dhi = __builtin_amdgcn_readlane((unsigned)(cur[k] >> 32), c);
      if (!((rml >> k) & 1u)) { rml |= dlo; rmh |= dhi; }
    }
#pragma unroll
    for (int k = 0; k < 32; ++k) {
      unsigned dlo = __builtin_amdgcn_readlane((unsigned)cur[k], 32 + c);
      unsigned dhi = __builtin_amdgcn_readlane((unsigned)(cur[k] >> 32), 32 + c);
      if (!((rmh >> k) & 1u)) { rml |= dlo; rmh |= dhi; }
    }
    u64 rmfull = ((u64)rmh << 32) | rml;
    u64 kb = ~rmfull;
    while (kb) {
      if (outCount >= DET_) return true;
      int k = __builtin_ctzll(kb);
      kb &= kb - 1;
      emitRow(c * 64 + k, true);
    }
    if (outCount >= DET_) return true;
    unsigned kmask = h ? ~rmh : ~rml;
    u64 acc = 0;
#pragma unroll
    for (int k = 0; k < 32; ++k)
      acc |= ((kmask >> k) & 1u) ? cur[k] : 0ull;
    acc |= __shfl_xor(acc, 32);
    removed = (l == c) ? rmfull : removed;
    if (l < 32 && l >= c) removed |= acc;
    return false;
  };

  bool done = false;
  loadc(ra, 0);
  for (int c = 0; c < NW_ && !done; c += 2) {
    if (c + 1 < NW_) loadc(rb, c + 1);
    done = chunk(ra, c);
    if (!done) {
      if (c + 2 < NW_) loadc(ra, c + 2);
      done = chunk(rb, c + 1);
    }
  }
  if (outCount < DET_) {
    for (int c2 = 0; c2 < NW_ && outCount < DET_; ++c2) {
      u64 rm = __shfl(removed, c2);
      while (rm && outCount < DET_) {
        int k = __builtin_ctzll(rm);
        rm &= rm - 1;
        emitRow(c2 * 64 + k, false);
      }
    }
  }
}

extern "C" void kernel_launch(void* const* d_in, const int* in_sizes, int n_in,
                              void* d_out, int out_size, void* d_ws, size_t ws_size,
                              hipStream_t stream) {
  const float* label_pre = (const float*)d_in[0];
  const float* bbox_pre = (const float*)d_in[1];
  const float* props = (const float*)d_in[2];
  float* out = (float*)d_out;

  char* ws = (char*)d_ws;
  size_t off = 0;
  auto alloc = [&](size_t bytes) -> void* {
    void* p = ws + off;
    off = (off + bytes + 255) & ~(size_t)255;
    return p;
  };

  uint32_t* keys = (uint32_t*)alloc((size_t)B_ * NC_ * 4);
  uint32_t* histPart = (uint32_t*)alloc((size_t)B_ * IB_ * CB_ * 4);  // written unconditionally
  // ---- single zero region, zero-stored by k_scores (all 256B multiples) ----
  size_t zero_begin = off;
  uint32_t* cnt = (uint32_t*)alloc((size_t)B_ * SLOTS_ * 16 * 4);     // 16384 B
  u64* cand = (u64*)alloc((size_t)B_ * CAND_ * 8);                    // 262144 B
  float* topScore = (float*)alloc((size_t)B_ * KP_ * 4);              // 65536 B
  int* topLabel = (int*)alloc((size_t)B_ * KP_ * 4);                  // 65536 B
  float* topBox = (float*)alloc((size_t)B_ * KP_ * 16);               // 524288 B
  float* nmsBox = (float*)alloc((size_t)B_ * KP_ * 16);               // 524288 B
  size_t zero_end = off;
  // ---- no zeroing needed ----
  u64* sup = (u64*)alloc((size_t)B_ * KP_ * NW_ * 8);
  uint32_t* rankPart = (uint32_t*)alloc((size_t)B_ * RJS_ * CAND_ * 4);

  if (off > ws_size) return;  // workspace too small -> fail visibly

  uint4* zr = (uint4*)(ws + zero_begin);
  int zrN = (int)((zero_end - zero_begin) / 16);

  k_scores<<<B_ * IB_, 256, 0, stream>>>(label_pre, keys, histPart, zr, zrN);
  k_compact<<<B_ * SEGB_, 256, 0, stream>>>(keys, histPart, cnt, cand);
  k_rank<<<B_ * RIB_ * RJS_, RT_, 0, stream>>>(cand, rankPart);
  k_scatter<<<B_ * IBK_, 256, 0, stream>>>(cand, rankPart, bbox_pre, props,
                                           topScore, topLabel, topBox, nmsBox);
  k_supmat<<<B_ * 528, 64, 0, stream>>>(nmsBox, sup);
  k_nms_scan<<<B_, 64, 0, stream>>>(sup, topScore, topLabel, topBox, out);
}